// Round 1
// baseline (9988.037 us; speedup 1.0000x reference)
//
#include <hip/hip_runtime.h>
#include <cstdint>
#include <cstddef>

// Problem constants (match reference)
#define NNODES 20000
#define NEDGES 640000
#define IN_F   128
#define CL1_F  256
#define CL2_F  128
#define OUT_F  10
#define BN_EPS 1e-5f

// ---------------- graph normalization ----------------

__global__ void deg_kernel(const int* __restrict__ ei, const float* __restrict__ ew,
                           float* __restrict__ deg, int E) {
    int e = blockIdx.x * blockDim.x + threadIdx.x;
    if (e >= E) return;
    int r = ei[e];
    int c = ei[E + e];
    float w = (r == c) ? 0.0f : ew[e];
    if (w != 0.0f) atomicAdd(&deg[r], w);
}

__global__ void dis_kernel(const float* __restrict__ deg, float* __restrict__ dis, int n) {
    int i = blockIdx.x * blockDim.x + threadIdx.x;
    if (i >= n) return;
    float d = deg[i];
    dis[i] = (d > 0.0f) ? (1.0f / sqrtf(d)) : 0.0f;
}

__global__ void wnorm_kernel(const int* __restrict__ ei, const float* __restrict__ ew,
                             const float* __restrict__ dis, float* __restrict__ wn, int E) {
    int e = blockIdx.x * blockDim.x + threadIdx.x;
    if (e >= E) return;
    int r = ei[e];
    int c = ei[E + e];
    float w = (r == c) ? 0.0f : ew[e];
    wn[e] = -(dis[r] * w * dis[c]);   // * (2/lambda_max) = *1
}

// ---------------- slice init / copy ----------------

// dst[n*ld + f] = x[n*F + f]   (copy x into slice 0 of A1)
__global__ void copy_to_slice(const float* __restrict__ src, float* __restrict__ dst,
                              int n_elems, int F, int ld) {
    int i = blockIdx.x * blockDim.x + threadIdx.x;
    if (i >= n_elems) return;
    int n = i / F, f = i - n * F;
    dst[(size_t)n * ld + f] = src[i];
}

// dst_slice = c * src_slice  (c==0 -> pure zero, no read)
__global__ void scale_slice(const float* __restrict__ src, float* __restrict__ dst,
                            int n_elems, int F, int ld, float c) {
    int i = blockIdx.x * blockDim.x + threadIdx.x;
    if (i >= n_elems) return;
    int n = i / F, f = i - n * F;
    size_t off = (size_t)n * ld + f;
    dst[off] = (c == 0.0f) ? 0.0f : c * src[off];
}

// ---------------- spmm scatter (atomics) ----------------
// out[col[e]] += s * wn[e] * in[row[e]]  over F features; float4 per thread
__global__ void spmm_scatter(const int* __restrict__ ei, const float* __restrict__ wn,
                             const float* __restrict__ tin, float* __restrict__ tout,
                             int E, int tpeShift, int ld, float s) {
    int gid = blockIdx.x * blockDim.x + threadIdx.x;
    int e = gid >> tpeShift;
    if (e >= E) return;
    int f4 = (gid & ((1 << tpeShift) - 1)) << 2;
    float w = s * wn[e];
    int r = ei[e];
    int c = ei[E + e];
    const float4 v = *(const float4*)(tin + (size_t)r * ld + f4);
    float* o = tout + (size_t)c * ld + f4;
    if (w != 0.0f) {
        atomicAdd(o + 0, w * v.x);
        atomicAdd(o + 1, w * v.y);
        atomicAdd(o + 2, w * v.z);
        atomicAdd(o + 3, w * v.w);
    }
}

// ---------------- fp32 GEMM, 64x64 tile, bias + optional relu ----------------
// C[M,N] = A[M,K](lda) @ B[K,N](ldb) + bias[N]; relu if doRelu
#define BM 64
#define BN 64
#define BK 16

__launch_bounds__(256)
__global__ void gemm_bias_relu(const float* __restrict__ A, const float* __restrict__ B,
                               const float* __restrict__ bias, float* __restrict__ C,
                               int M, int N, int K, int lda, int ldb, int ldc, int doRelu) {
    __shared__ float As[BK][BM + 4];   // +4 keeps float4 alignment (68*4 = 17*16B)
    __shared__ float Bs[BK][BN];

    int tid = threadIdx.x;
    int tx = tid & 15, ty = tid >> 4;
    int rowBase = blockIdx.x * BM;
    int colBase = blockIdx.y * BN;

    int am = tid >> 2;           // 0..63  (row within A tile)
    int ak = (tid & 3) * 4;      // 0,4,8,12
    int bk = tid >> 4;           // 0..15
    int bn = (tid & 15) * 4;     // 0..60

    float acc[4][4] = {};

    for (int k0 = 0; k0 < K; k0 += BK) {
        float4 av = make_float4(0.f, 0.f, 0.f, 0.f);
        int gm = rowBase + am;
        if (gm < M) av = *(const float4*)(A + (size_t)gm * lda + k0 + ak);
        As[ak + 0][am] = av.x;
        As[ak + 1][am] = av.y;
        As[ak + 2][am] = av.z;
        As[ak + 3][am] = av.w;

        float4 bv = *(const float4*)(B + (size_t)(k0 + bk) * ldb + colBase + bn);
        *(float4*)&Bs[bk][bn] = bv;

        __syncthreads();
#pragma unroll
        for (int k = 0; k < BK; ++k) {
            float4 a = *(const float4*)&As[k][ty * 4];
            float4 b = *(const float4*)&Bs[k][tx * 4];
            acc[0][0] += a.x * b.x; acc[0][1] += a.x * b.y; acc[0][2] += a.x * b.z; acc[0][3] += a.x * b.w;
            acc[1][0] += a.y * b.x; acc[1][1] += a.y * b.y; acc[1][2] += a.y * b.z; acc[1][3] += a.y * b.w;
            acc[2][0] += a.z * b.x; acc[2][1] += a.z * b.y; acc[2][2] += a.z * b.z; acc[2][3] += a.z * b.w;
            acc[3][0] += a.w * b.x; acc[3][1] += a.w * b.y; acc[3][2] += a.w * b.z; acc[3][3] += a.w * b.w;
        }
        __syncthreads();
    }

#pragma unroll
    for (int i = 0; i < 4; ++i) {
        int m = rowBase + ty * 4 + i;
        if (m >= M) continue;
#pragma unroll
        for (int j = 0; j < 4; ++j) {
            int n = colBase + tx * 4 + j;
            float v = acc[i][j] + bias[n];
            if (doRelu) v = fmaxf(v, 0.0f);
            C[(size_t)m * ldc + n] = v;
        }
    }
}

// ---------------- batchnorm ----------------

#define BN_ROWS 64
// blockDim.x == C; each block reduces BN_ROWS rows
__global__ void bn_stats(const float* __restrict__ h, int N, int C,
                         float* __restrict__ sums, float* __restrict__ sumsq) {
    int c = threadIdx.x;
    int r0 = blockIdx.x * BN_ROWS;
    int r1 = min(r0 + BN_ROWS, N);
    float s = 0.f, q = 0.f;
    for (int r = r0; r < r1; ++r) {
        float v = h[(size_t)r * C + c];
        s += v;
        q += v * v;
    }
    atomicAdd(&sums[c], s);
    atomicAdd(&sumsq[c], q);
}

__global__ void bn_final(const float* __restrict__ sums, const float* __restrict__ sumsq,
                         const float* __restrict__ gamma, const float* __restrict__ beta,
                         float* __restrict__ scale, float* __restrict__ shift, int C, float invN) {
    int c = threadIdx.x + blockIdx.x * blockDim.x;
    if (c >= C) return;
    float m = sums[c] * invN;
    float var = sumsq[c] * invN - m * m;
    float sc = gamma[c] / sqrtf(var + BN_EPS);
    scale[c] = sc;
    shift[c] = beta[c] - m * sc;
}

// out[n*ldo + c] = h[n*C + c]*scale[c] + shift[c]
__global__ void bn_apply(const float* __restrict__ h, const float* __restrict__ scale,
                         const float* __restrict__ shift, float* __restrict__ out,
                         int n_elems, int C, int ldo) {
    int i = blockIdx.x * blockDim.x + threadIdx.x;
    if (i >= n_elems) return;
    int n = i / C, c = i - n * C;
    out[(size_t)n * ldo + c] = h[i] * scale[c] + shift[c];
}

// ---------------- final linear: out[N,10] = g[N,128] @ Wlin^T + blin ----------------

__global__ void final_linear(const float* __restrict__ g, const float* __restrict__ Wlin,
                             const float* __restrict__ blin, float* __restrict__ out, int N) {
    __shared__ float Ws[OUT_F * CL2_F];
    __shared__ float bs[OUT_F];
    for (int i = threadIdx.x; i < OUT_F * CL2_F; i += 256) Ws[i] = Wlin[i];
    if (threadIdx.x < OUT_F) bs[threadIdx.x] = blin[threadIdx.x];
    __syncthreads();
    int idx = blockIdx.x * 256 + threadIdx.x;
    if (idx >= N * OUT_F) return;
    int n = idx / OUT_F, o = idx - n * OUT_F;
    const float* gr = g + (size_t)n * CL2_F;
    const float* wr = Ws + o * CL2_F;
    float acc = 0.f;
#pragma unroll 8
    for (int f = 0; f < CL2_F; ++f) acc += gr[f] * wr[f];
    out[idx] = acc + bs[o];
}

// ---------------- host launch ----------------

extern "C" void kernel_launch(void* const* d_in, const int* in_sizes, int n_in,
                              void* d_out, int out_size, void* d_ws, size_t ws_size,
                              hipStream_t stream) {
    const float* x     = (const float*)d_in[0];
    const int*   ei    = (const int*)d_in[1];
    const float* ew    = (const float*)d_in[2];
    const float* W1    = (const float*)d_in[3];   // (4,128,256) -> (512,256)
    const float* b1    = (const float*)d_in[4];
    const float* W2    = (const float*)d_in[5];   // (4,256,128) -> (1024,128)
    const float* b2    = (const float*)d_in[6];
    const float* gamma1 = (const float*)d_in[7];
    const float* beta1  = (const float*)d_in[8];
    const float* gamma2 = (const float*)d_in[9];
    const float* beta2  = (const float*)d_in[10];
    const float* Wlin  = (const float*)d_in[11];
    const float* blin  = (const float*)d_in[12];
    float* out = (float*)d_out;

    const int N = NNODES, E = NEDGES;

    // workspace layout (A1 aliases A2 region; h2 aliases h1 region)
    char* base = (char*)d_ws;
    float* A2   = (float*)(base + 0);                 // N*1024 fp32 = 81.92 MB
    float* A1   = A2;                                  // N*512  fp32 (dead before A2 is written)
    float* h1   = (float*)(base + 81920000);           // N*256 = 20.48 MB
    float* h2   = h1;                                  // N*128 (h1 dead before h2 written)
    float* wn   = (float*)(base + 102400000);          // E fp32 = 2.56 MB
    float* deg  = (float*)(base + 104960000);          // N fp32
    float* dis  = (float*)(base + 105040000);          // N fp32
    float* bns  = (float*)(base + 105120000);          // 256 sums
    float* bnq  = bns + 256;                           // 256 sumsq
    float* bnscale = bnq + 256;
    float* bnshift = bnscale + 256;

    dim3 blk(256);

    // --- normalization ---
    hipMemsetAsync(deg, 0, N * sizeof(float), stream);
    deg_kernel<<<dim3((E + 255) / 256), blk, 0, stream>>>(ei, ew, deg, E);
    dis_kernel<<<dim3((N + 255) / 256), blk, 0, stream>>>(deg, dis, N);
    wnorm_kernel<<<dim3((E + 255) / 256), blk, 0, stream>>>(ei, ew, dis, wn, E);

    // --- layer 1: build A1 = [Tx0|Tx1|Tx2|Tx3], F=128, ld=512 ---
    {
        const int F = 128, LD = 512;
        int nEl = N * F;
        dim3 gEl((nEl + 255) / 256);
        dim3 gSc((E * (F / 4) + 255) / 256);
        copy_to_slice<<<gEl, blk, 0, stream>>>(x, A1 + 0, nEl, F, LD);
        // Tx1 = spmm(Tx0)
        scale_slice<<<gEl, blk, 0, stream>>>(A1, A1 + F, nEl, F, LD, 0.0f);
        spmm_scatter<<<gSc, blk, 0, stream>>>(ei, wn, A1 + 0, A1 + F, E, 5, LD, 1.0f);
        // Tx2 = 2*spmm(Tx1) - Tx0
        scale_slice<<<gEl, blk, 0, stream>>>(A1 + 0, A1 + 2 * F, nEl, F, LD, -1.0f);
        spmm_scatter<<<gSc, blk, 0, stream>>>(ei, wn, A1 + F, A1 + 2 * F, E, 5, LD, 2.0f);
        // Tx3 = 2*spmm(Tx2) - Tx1
        scale_slice<<<gEl, blk, 0, stream>>>(A1 + F, A1 + 3 * F, nEl, F, LD, -1.0f);
        spmm_scatter<<<gSc, blk, 0, stream>>>(ei, wn, A1 + 2 * F, A1 + 3 * F, E, 5, LD, 2.0f);
    }

    // --- GEMM1: h1 = relu(A1 @ W1s + b1), M=20000 K=512 N=256 ---
    gemm_bias_relu<<<dim3((N + BM - 1) / BM, CL1_F / BN), blk, 0, stream>>>(
        A1, W1, b1, h1, N, CL1_F, 512, 512, CL1_F, CL1_F, 1);

    // --- BN1 -> A2 slice 0 (ld 1024) ---
    hipMemsetAsync(bns, 0, 2 * 256 * sizeof(float), stream);
    bn_stats<<<dim3((N + BN_ROWS - 1) / BN_ROWS), dim3(CL1_F), 0, stream>>>(h1, N, CL1_F, bns, bnq);
    bn_final<<<dim3(1), dim3(CL1_F), 0, stream>>>(bns, bnq, gamma1, beta1, bnscale, bnshift, CL1_F, 1.0f / N);
    bn_apply<<<dim3((N * CL1_F + 255) / 256), blk, 0, stream>>>(h1, bnscale, bnshift, A2 + 0, N * CL1_F, CL1_F, 1024);

    // --- layer 2: A2 slices, F=256, ld=1024 ---
    {
        const int F = 256, LD = 1024;
        int nEl = N * F;
        dim3 gEl((nEl + 255) / 256);
        dim3 gSc((E * (F / 4) + 255) / 256);
        scale_slice<<<gEl, blk, 0, stream>>>(A2, A2 + F, nEl, F, LD, 0.0f);
        spmm_scatter<<<gSc, blk, 0, stream>>>(ei, wn, A2 + 0, A2 + F, E, 6, LD, 1.0f);
        scale_slice<<<gEl, blk, 0, stream>>>(A2 + 0, A2 + 2 * F, nEl, F, LD, -1.0f);
        spmm_scatter<<<gSc, blk, 0, stream>>>(ei, wn, A2 + F, A2 + 2 * F, E, 6, LD, 2.0f);
        scale_slice<<<gEl, blk, 0, stream>>>(A2 + F, A2 + 3 * F, nEl, F, LD, -1.0f);
        spmm_scatter<<<gSc, blk, 0, stream>>>(ei, wn, A2 + 2 * F, A2 + 3 * F, E, 6, LD, 2.0f);
    }

    // --- GEMM2: h2 = relu(A2 @ W2s + b2), M=20000 K=1024 N=128 ---
    gemm_bias_relu<<<dim3((N + BM - 1) / BM, CL2_F / BN), blk, 0, stream>>>(
        A2, W2, b2, h2, N, CL2_F, 1024, 1024, CL2_F, CL2_F, 1);

    // --- BN2 in-place on h2 ---
    hipMemsetAsync(bns, 0, 2 * 256 * sizeof(float), stream);
    bn_stats<<<dim3((N + BN_ROWS - 1) / BN_ROWS), dim3(CL2_F), 0, stream>>>(h2, N, CL2_F, bns, bnq);
    bn_final<<<dim3(1), dim3(CL2_F), 0, stream>>>(bns, bnq, gamma2, beta2, bnscale, bnshift, CL2_F, 1.0f / N);
    bn_apply<<<dim3((N * CL2_F + 255) / 256), blk, 0, stream>>>(h2, bnscale, bnshift, h2, N * CL2_F, CL2_F, CL2_F);

    // --- final linear ---
    final_linear<<<dim3((N * OUT_F + 255) / 256), blk, 0, stream>>>(h2, Wlin, blin, out, N);
}

// Round 2
// 886.510 us; speedup vs baseline: 11.2667x; 11.2667x over previous
//
#include <hip/hip_runtime.h>
#include <cstdint>
#include <cstddef>

// Problem constants (match reference)
#define NNODES 20000
#define NEDGES 640000
#define IN_F   128
#define CL1_F  256
#define CL2_F  128
#define OUT_F  10
#define BN_EPS 1e-5f

// ---------------- graph normalization + CSC count ----------------

// deg[row] += w (self-loops removed); cnt[col] += 1
__global__ void count_deg(const int* __restrict__ ei, const float* __restrict__ ew,
                          float* __restrict__ deg, int* __restrict__ cnt, int E) {
    int e = blockIdx.x * blockDim.x + threadIdx.x;
    if (e >= E) return;
    int r = ei[e];
    int c = ei[E + e];
    float w = (r == c) ? 0.0f : ew[e];
    if (w != 0.0f) atomicAdd(&deg[r], w);
    atomicAdd(&cnt[c], 1);
}

__global__ void dis_kernel(const float* __restrict__ deg, float* __restrict__ dis, int n) {
    int i = blockIdx.x * blockDim.x + threadIdx.x;
    if (i >= n) return;
    float d = deg[i];
    dis[i] = (d > 0.0f) ? (1.0f / sqrtf(d)) : 0.0f;
}

// single-block exclusive scan of cnt[0..N) -> rowptr[0..N], also copies into off[]
__global__ void scan_kernel(const int* __restrict__ cnt, int* __restrict__ rowptr,
                            int* __restrict__ off, int N) {
    __shared__ int sums[256];
    int t = threadIdx.x;
    int per = (N + 255) / 256;
    int s0 = t * per, s1 = min(s0 + per, N);
    int s = 0;
    for (int i = s0; i < s1; ++i) s += cnt[i];
    sums[t] = s;
    __syncthreads();
    if (t == 0) {
        int run = 0;
        for (int i = 0; i < 256; ++i) { int v = sums[i]; sums[i] = run; run += v; }
        rowptr[N] = run;
    }
    __syncthreads();
    int run = sums[t];
    for (int i = s0; i < s1; ++i) { rowptr[i] = run; off[i] = run; run += cnt[i]; }
}

// scatter edges into CSC order; normalized weight computed inline
__global__ void fill_edges(const int* __restrict__ ei, const float* __restrict__ ew,
                           const float* __restrict__ dis, int* __restrict__ off,
                           int* __restrict__ esrc, float* __restrict__ ewn, int E) {
    int e = blockIdx.x * blockDim.x + threadIdx.x;
    if (e >= E) return;
    int r = ei[e];
    int c = ei[E + e];
    float w = (r == c) ? 0.0f : ew[e];
    float wn = -(dis[r] * w * dis[c]);   // * (2/lambda_max) = *1
    int pos = atomicAdd(&off[c], 1);
    esrc[pos] = r;
    ewn[pos] = wn;
}

// ---------------- slice copy ----------------

__global__ void copy_to_slice(const float* __restrict__ src, float* __restrict__ dst,
                              int n_elems, int F, int ld) {
    int i = blockIdx.x * blockDim.x + threadIdx.x;
    if (i >= n_elems) return;
    int n = i / F, f = i - n * F;
    dst[(size_t)n * ld + f] = src[i];
}

// ---------------- spmm gather (CSC, no atomics) ----------------
// tout[n] = s * sum_{p in [rowptr[n],rowptr[n+1])} ewn[p] * tin[esrc[p]]  - tprev[n]
// (tprev==nullptr -> no subtraction). One thread per (node, 4-feature group).
__launch_bounds__(256)
__global__ void spmm_gather(const int* __restrict__ rowptr, const int* __restrict__ esrc,
                            const float* __restrict__ ewn, const float* __restrict__ tin,
                            const float* __restrict__ tprev, float* __restrict__ tout,
                            int N, int f4shift, int ld, float s) {
    int gid = blockIdx.x * blockDim.x + threadIdx.x;
    int n = gid >> f4shift;
    if (n >= N) return;
    int f = (gid & ((1 << f4shift) - 1)) << 2;
    int p = rowptr[n], pe = rowptr[n + 1];
    float ax = 0.f, ay = 0.f, az = 0.f, aw = 0.f;
    for (; p + 1 < pe; p += 2) {
        int sa = esrc[p], sb = esrc[p + 1];
        float wa = ewn[p], wb = ewn[p + 1];
        const float4 va = *(const float4*)(tin + (size_t)sa * ld + f);
        const float4 vb = *(const float4*)(tin + (size_t)sb * ld + f);
        ax += wa * va.x + wb * vb.x;
        ay += wa * va.y + wb * vb.y;
        az += wa * va.z + wb * vb.z;
        aw += wa * va.w + wb * vb.w;
    }
    if (p < pe) {
        int sa = esrc[p];
        float wa = ewn[p];
        const float4 va = *(const float4*)(tin + (size_t)sa * ld + f);
        ax += wa * va.x; ay += wa * va.y; az += wa * va.z; aw += wa * va.w;
    }
    float4 o;
    if (tprev) {
        const float4 pv = *(const float4*)(tprev + (size_t)n * ld + f);
        o.x = s * ax - pv.x; o.y = s * ay - pv.y; o.z = s * az - pv.z; o.w = s * aw - pv.w;
    } else {
        o.x = s * ax; o.y = s * ay; o.z = s * az; o.w = s * aw;
    }
    *(float4*)(tout + (size_t)n * ld + f) = o;
}

// ---------------- fp32 GEMM, 64x64 tile, bias + optional relu ----------------
#define BM 64
#define BNT 64
#define BK 16

__launch_bounds__(256)
__global__ void gemm_bias_relu(const float* __restrict__ A, const float* __restrict__ B,
                               const float* __restrict__ bias, float* __restrict__ C,
                               int M, int N, int K, int lda, int ldb, int ldc, int doRelu) {
    __shared__ float As[BK][BM + 4];
    __shared__ float Bs[BK][BNT];

    int tid = threadIdx.x;
    int tx = tid & 15, ty = tid >> 4;
    int rowBase = blockIdx.x * BM;
    int colBase = blockIdx.y * BNT;

    int am = tid >> 2;
    int ak = (tid & 3) * 4;
    int bk = tid >> 4;
    int bn = (tid & 15) * 4;

    float acc[4][4] = {};

    for (int k0 = 0; k0 < K; k0 += BK) {
        float4 av = make_float4(0.f, 0.f, 0.f, 0.f);
        int gm = rowBase + am;
        if (gm < M) av = *(const float4*)(A + (size_t)gm * lda + k0 + ak);
        As[ak + 0][am] = av.x;
        As[ak + 1][am] = av.y;
        As[ak + 2][am] = av.z;
        As[ak + 3][am] = av.w;

        float4 bv = *(const float4*)(B + (size_t)(k0 + bk) * ldb + colBase + bn);
        *(float4*)&Bs[bk][bn] = bv;

        __syncthreads();
#pragma unroll
        for (int k = 0; k < BK; ++k) {
            float4 a = *(const float4*)&As[k][ty * 4];
            float4 b = *(const float4*)&Bs[k][tx * 4];
            acc[0][0] += a.x * b.x; acc[0][1] += a.x * b.y; acc[0][2] += a.x * b.z; acc[0][3] += a.x * b.w;
            acc[1][0] += a.y * b.x; acc[1][1] += a.y * b.y; acc[1][2] += a.y * b.z; acc[1][3] += a.y * b.w;
            acc[2][0] += a.z * b.x; acc[2][1] += a.z * b.y; acc[2][2] += a.z * b.z; acc[2][3] += a.z * b.w;
            acc[3][0] += a.w * b.x; acc[3][1] += a.w * b.y; acc[3][2] += a.w * b.z; acc[3][3] += a.w * b.w;
        }
        __syncthreads();
    }

#pragma unroll
    for (int i = 0; i < 4; ++i) {
        int m = rowBase + ty * 4 + i;
        if (m >= M) continue;
#pragma unroll
        for (int j = 0; j < 4; ++j) {
            int n = colBase + tx * 4 + j;
            float v = acc[i][j] + bias[n];
            if (doRelu) v = fmaxf(v, 0.0f);
            C[(size_t)m * ldc + n] = v;
        }
    }
}

// ---------------- batchnorm ----------------

#define BN_ROWS 64
__global__ void bn_stats(const float* __restrict__ h, int N, int C,
                         float* __restrict__ sums, float* __restrict__ sumsq) {
    int c = threadIdx.x;
    int r0 = blockIdx.x * BN_ROWS;
    int r1 = min(r0 + BN_ROWS, N);
    float s = 0.f, q = 0.f;
    for (int r = r0; r < r1; ++r) {
        float v = h[(size_t)r * C + c];
        s += v;
        q += v * v;
    }
    atomicAdd(&sums[c], s);
    atomicAdd(&sumsq[c], q);
}

__global__ void bn_final(const float* __restrict__ sums, const float* __restrict__ sumsq,
                         const float* __restrict__ gamma, const float* __restrict__ beta,
                         float* __restrict__ scale, float* __restrict__ shift, int C, float invN) {
    int c = threadIdx.x + blockIdx.x * blockDim.x;
    if (c >= C) return;
    float m = sums[c] * invN;
    float var = sumsq[c] * invN - m * m;
    float sc = gamma[c] / sqrtf(var + BN_EPS);
    scale[c] = sc;
    shift[c] = beta[c] - m * sc;
}

__global__ void bn_apply(const float* __restrict__ h, const float* __restrict__ scale,
                         const float* __restrict__ shift, float* __restrict__ out,
                         int n_elems, int C, int ldo) {
    int i = blockIdx.x * blockDim.x + threadIdx.x;
    if (i >= n_elems) return;
    int n = i / C, c = i - n * C;
    out[(size_t)n * ldo + c] = h[i] * scale[c] + shift[c];
}

// ---------------- final linear ----------------

__global__ void final_linear(const float* __restrict__ g, const float* __restrict__ Wlin,
                             const float* __restrict__ blin, float* __restrict__ out, int N) {
    __shared__ float Ws[OUT_F * CL2_F];
    __shared__ float bs[OUT_F];
    for (int i = threadIdx.x; i < OUT_F * CL2_F; i += 256) Ws[i] = Wlin[i];
    if (threadIdx.x < OUT_F) bs[threadIdx.x] = blin[threadIdx.x];
    __syncthreads();
    int idx = blockIdx.x * 256 + threadIdx.x;
    if (idx >= N * OUT_F) return;
    int n = idx / OUT_F, o = idx - n * OUT_F;
    const float* gr = g + (size_t)n * CL2_F;
    const float* wr = Ws + o * CL2_F;
    float acc = 0.f;
#pragma unroll 8
    for (int f = 0; f < CL2_F; ++f) acc += gr[f] * wr[f];
    out[idx] = acc + bs[o];
}

// ---------------- host launch ----------------

extern "C" void kernel_launch(void* const* d_in, const int* in_sizes, int n_in,
                              void* d_out, int out_size, void* d_ws, size_t ws_size,
                              hipStream_t stream) {
    const float* x      = (const float*)d_in[0];
    const int*   ei     = (const int*)d_in[1];
    const float* ew     = (const float*)d_in[2];
    const float* W1     = (const float*)d_in[3];   // (4,128,256) -> (512,256)
    const float* b1     = (const float*)d_in[4];
    const float* W2     = (const float*)d_in[5];   // (4,256,128) -> (1024,128)
    const float* b2     = (const float*)d_in[6];
    const float* gamma1 = (const float*)d_in[7];
    const float* beta1  = (const float*)d_in[8];
    const float* gamma2 = (const float*)d_in[9];
    const float* beta2  = (const float*)d_in[10];
    const float* Wlin   = (const float*)d_in[11];
    const float* blin   = (const float*)d_in[12];
    float* out = (float*)d_out;

    const int N = NNODES, E = NEDGES;

    // workspace layout (~108 MB)
    char* base = (char*)d_ws;
    float* A2     = (float*)(base + 0);             // N*1024 fp32 = 81.92 MB
    float* A1     = A2;                             // N*512 (dead before A2 fully written)
    float* h1     = (float*)(base + 81920000);      // N*256 = 20.48 MB
    float* h2     = h1;                             // N*128
    int*   esrc   = (int*)  (base + 102400000);     // E = 2.56 MB
    float* ewn    = (float*)(base + 104960000);     // E = 2.56 MB
    int*   rowptr = (int*)  (base + 107520000);     // N+1
    int*   off    = (int*)  (base + 107600016);     // N
    int*   cnt    = (int*)  (base + 107680016);     // N
    float* deg    = (float*)(base + 107760016);     // N
    float* dis    = (float*)(base + 107840016);     // N
    float* bns    = (float*)(base + 107920016);     // 256
    float* bnq     = bns + 256;
    float* bnscale = bnq + 256;
    float* bnshift = bnscale + 256;

    dim3 blk(256);

    // --- build normalized CSC ---
    hipMemsetAsync(cnt, 0, N * sizeof(int), stream);
    hipMemsetAsync(deg, 0, N * sizeof(float), stream);
    count_deg<<<dim3((E + 255) / 256), blk, 0, stream>>>(ei, ew, deg, cnt, E);
    dis_kernel<<<dim3((N + 255) / 256), blk, 0, stream>>>(deg, dis, N);
    scan_kernel<<<dim3(1), blk, 0, stream>>>(cnt, rowptr, off, N);
    fill_edges<<<dim3((E + 255) / 256), blk, 0, stream>>>(ei, ew, dis, off, esrc, ewn, E);

    // --- layer 1: A1 = [Tx0|Tx1|Tx2|Tx3], F=128, ld=512 ---
    {
        const int F = 128, LD = 512, SH = 5;
        dim3 gEl((N * F + 255) / 256);
        dim3 gG(((N << SH) + 255) / 256);
        copy_to_slice<<<gEl, blk, 0, stream>>>(x, A1 + 0, N * F, F, LD);
        spmm_gather<<<gG, blk, 0, stream>>>(rowptr, esrc, ewn, A1 + 0,     nullptr, A1 + F,     N, SH, LD, 1.0f);
        spmm_gather<<<gG, blk, 0, stream>>>(rowptr, esrc, ewn, A1 + F,     A1 + 0,  A1 + 2 * F, N, SH, LD, 2.0f);
        spmm_gather<<<gG, blk, 0, stream>>>(rowptr, esrc, ewn, A1 + 2 * F, A1 + F,  A1 + 3 * F, N, SH, LD, 2.0f);
    }

    // --- GEMM1: h1 = relu(A1 @ W1s + b1), M=20000 K=512 N=256 ---
    gemm_bias_relu<<<dim3((N + BM - 1) / BM, CL1_F / BNT), blk, 0, stream>>>(
        A1, W1, b1, h1, N, CL1_F, 512, 512, CL1_F, CL1_F, 1);

    // --- BN1 -> A2 slice 0 (ld 1024) ---
    hipMemsetAsync(bns, 0, 2 * 256 * sizeof(float), stream);
    bn_stats<<<dim3((N + BN_ROWS - 1) / BN_ROWS), dim3(CL1_F), 0, stream>>>(h1, N, CL1_F, bns, bnq);
    bn_final<<<dim3(1), dim3(CL1_F), 0, stream>>>(bns, bnq, gamma1, beta1, bnscale, bnshift, CL1_F, 1.0f / N);
    bn_apply<<<dim3((N * CL1_F + 255) / 256), blk, 0, stream>>>(h1, bnscale, bnshift, A2 + 0, N * CL1_F, CL1_F, 1024);

    // --- layer 2: A2 slices, F=256, ld=1024 ---
    {
        const int F = 256, LD = 1024, SH = 6;
        dim3 gG(((N << SH) + 255) / 256);
        spmm_gather<<<gG, blk, 0, stream>>>(rowptr, esrc, ewn, A2 + 0,     nullptr, A2 + F,     N, SH, LD, 1.0f);
        spmm_gather<<<gG, blk, 0, stream>>>(rowptr, esrc, ewn, A2 + F,     A2 + 0,  A2 + 2 * F, N, SH, LD, 2.0f);
        spmm_gather<<<gG, blk, 0, stream>>>(rowptr, esrc, ewn, A2 + 2 * F, A2 + F,  A2 + 3 * F, N, SH, LD, 2.0f);
    }

    // --- GEMM2: h2 = relu(A2 @ W2s + b2), M=20000 K=1024 N=128 ---
    gemm_bias_relu<<<dim3((N + BM - 1) / BM, CL2_F / BNT), blk, 0, stream>>>(
        A2, W2, b2, h2, N, CL2_F, 1024, 1024, CL2_F, CL2_F, 1);

    // --- BN2 in-place on h2 ---
    hipMemsetAsync(bns, 0, 2 * 256 * sizeof(float), stream);
    bn_stats<<<dim3((N + BN_ROWS - 1) / BN_ROWS), dim3(CL2_F), 0, stream>>>(h2, N, CL2_F, bns, bnq);
    bn_final<<<dim3(1), dim3(CL2_F), 0, stream>>>(bns, bnq, gamma2, beta2, bnscale, bnshift, CL2_F, 1.0f / N);
    bn_apply<<<dim3((N * CL2_F + 255) / 256), blk, 0, stream>>>(h2, bnscale, bnshift, h2, N * CL2_F, CL2_F, CL2_F);

    // --- final linear ---
    final_linear<<<dim3((N * OUT_F + 255) / 256), blk, 0, stream>>>(h2, Wlin, blin, out, N);
}

// Round 3
// 595.820 us; speedup vs baseline: 16.7635x; 1.4879x over previous
//
#include <hip/hip_runtime.h>
#include <cstdint>
#include <cstddef>

// Problem constants (match reference)
#define NNODES 20000
#define NEDGES 640000
#define IN_F   128
#define CL1_F  256
#define CL2_F  128
#define OUT_F  10
#define BN_EPS 1e-5f

typedef unsigned short u16;

// ---------------- bf16 helpers ----------------

__device__ __forceinline__ float bf2f(u16 u) {
    union { uint32_t i; float f; } v; v.i = ((uint32_t)u) << 16; return v.f;
}
__device__ __forceinline__ u16 f2bf(float f) {
    union { float f; uint32_t i; } v; v.f = f;
    uint32_t r = v.i + 0x7fffu + ((v.i >> 16) & 1u);   // RNE
    return (u16)(r >> 16);
}
__device__ __forceinline__ void bf2x2(uint32_t u, float& lo, float& hi) {
    union { uint32_t i; float f; } a, b;
    a.i = u << 16; b.i = u & 0xffff0000u;
    lo = a.f; hi = b.f;
}
__device__ __forceinline__ uint32_t f2bf2(float lo, float hi) {
    return (uint32_t)f2bf(lo) | ((uint32_t)f2bf(hi) << 16);
}
__device__ __forceinline__ void unpack8(uint4 v, float* o) {
    bf2x2(v.x, o[0], o[1]); bf2x2(v.y, o[2], o[3]);
    bf2x2(v.z, o[4], o[5]); bf2x2(v.w, o[6], o[7]);
}

// ---------------- graph normalization + CSC build ----------------

__global__ void count_deg(const int* __restrict__ ei, const float* __restrict__ ew,
                          float* __restrict__ deg, int* __restrict__ cnt, int E) {
    int e = blockIdx.x * blockDim.x + threadIdx.x;
    if (e >= E) return;
    int r = ei[e];
    int c = ei[E + e];
    float w = (r == c) ? 0.0f : ew[e];
    if (w != 0.0f) atomicAdd(&deg[r], w);
    atomicAdd(&cnt[c], 1);
}

__global__ void dis_kernel(const float* __restrict__ deg, float* __restrict__ dis, int n) {
    int i = blockIdx.x * blockDim.x + threadIdx.x;
    if (i >= n) return;
    float d = deg[i];
    dis[i] = (d > 0.0f) ? (1.0f / sqrtf(d)) : 0.0f;
}

__global__ void scan_kernel(const int* __restrict__ cnt, int* __restrict__ rowptr,
                            int* __restrict__ off, int N) {
    __shared__ int sums[256];
    int t = threadIdx.x;
    int per = (N + 255) / 256;
    int s0 = t * per, s1 = min(s0 + per, N);
    int s = 0;
    for (int i = s0; i < s1; ++i) s += cnt[i];
    sums[t] = s;
    __syncthreads();
    if (t == 0) {
        int run = 0;
        for (int i = 0; i < 256; ++i) { int v = sums[i]; sums[i] = run; run += v; }
        rowptr[N] = run;
    }
    __syncthreads();
    int run = sums[t];
    for (int i = s0; i < s1; ++i) { rowptr[i] = run; off[i] = run; run += cnt[i]; }
}

__global__ void fill_edges(const int* __restrict__ ei, const float* __restrict__ ew,
                           const float* __restrict__ dis, int* __restrict__ off,
                           int* __restrict__ esrc, float* __restrict__ ewn, int E) {
    int e = blockIdx.x * blockDim.x + threadIdx.x;
    if (e >= E) return;
    int r = ei[e];
    int c = ei[E + e];
    float w = (r == c) ? 0.0f : ew[e];
    float wn = -(dis[r] * w * dis[c]);   // * (2/lambda_max) = *1
    int pos = atomicAdd(&off[c], 1);
    esrc[pos] = r;
    ewn[pos] = wn;
}

// ---------------- conversions ----------------

// x [N,F] fp32 -> bf16 slice (ld elements)
__global__ void conv_x_bf(const float* __restrict__ x, u16* __restrict__ dst,
                          int n_elems, int F, int ld) {
    int i = blockIdx.x * blockDim.x + threadIdx.x;
    if (i >= n_elems) return;
    int n = i / F, f = i - n * F;
    dst[(size_t)n * ld + f] = f2bf(x[i]);
}

// W [KK,NN] fp32 row-major -> Wt [NN,KK] bf16 row-major
__global__ void conv_w_t(const float* __restrict__ W, u16* __restrict__ Wt, int KK, int NN) {
    int i = blockIdx.x * blockDim.x + threadIdx.x;
    if (i >= KK * NN) return;
    int k = i / NN, n = i - k * NN;
    Wt[(size_t)n * KK + k] = f2bf(W[i]);
}

// ---------------- spmm gather (CSC, bf16 in/out, fp32 accumulate) ----------------
// tout[n] = s * sum_p ewn[p] * tin[esrc[p]] - tprev[n]   (tprev==nullptr -> no sub)
// One thread per (node, 8-feature group).
__launch_bounds__(256)
__global__ void spmm_gather_bf(const int* __restrict__ rowptr, const int* __restrict__ esrc,
                               const float* __restrict__ ewn, const u16* __restrict__ tin,
                               const u16* __restrict__ tprev, u16* __restrict__ tout,
                               int N, int f8shift, int ld, float s) {
    int gid = blockIdx.x * blockDim.x + threadIdx.x;
    int n = gid >> f8shift;
    if (n >= N) return;
    int f = (gid & ((1 << f8shift) - 1)) << 3;
    int p = rowptr[n], pe = rowptr[n + 1];
    float acc[8] = {};
    for (; p + 1 < pe; p += 2) {
        int sa = esrc[p], sb = esrc[p + 1];
        float wa = ewn[p], wb = ewn[p + 1];
        uint4 va = *(const uint4*)(tin + (size_t)sa * ld + f);
        uint4 vb = *(const uint4*)(tin + (size_t)sb * ld + f);
        float fa[8], fb[8];
        unpack8(va, fa); unpack8(vb, fb);
#pragma unroll
        for (int q = 0; q < 8; ++q) acc[q] += wa * fa[q] + wb * fb[q];
    }
    if (p < pe) {
        int sa = esrc[p];
        float wa = ewn[p];
        uint4 va = *(const uint4*)(tin + (size_t)sa * ld + f);
        float fa[8];
        unpack8(va, fa);
#pragma unroll
        for (int q = 0; q < 8; ++q) acc[q] += wa * fa[q];
    }
    if (tprev) {
        uint4 pv = *(const uint4*)(tprev + (size_t)n * ld + f);
        float fp[8];
        unpack8(pv, fp);
#pragma unroll
        for (int q = 0; q < 8; ++q) acc[q] = s * acc[q] - fp[q];
    } else {
#pragma unroll
        for (int q = 0; q < 8; ++q) acc[q] *= s;
    }
    uint4 o;
    o.x = f2bf2(acc[0], acc[1]);
    o.y = f2bf2(acc[2], acc[3]);
    o.z = f2bf2(acc[4], acc[5]);
    o.w = f2bf2(acc[6], acc[7]);
    *(uint4*)(tout + (size_t)n * ld + f) = o;
}

// ---------------- bf16 MFMA GEMM ----------------
// C[M,N] fp32 = A[M,K] bf16 (lda=K) @ Bt[N,K] bf16 (ldb=K, pre-transposed) + bias; relu opt.
// Block: 64x64 tile, 4 waves as 2x2 of 32x32 (2x2 of 16x16 mfma each). BK=64.

typedef __attribute__((ext_vector_type(8))) short short8;
typedef __attribute__((ext_vector_type(4))) float floatx4;

#define GBM 64
#define GBN 64
#define GBK 64

__launch_bounds__(256)
__global__ void gemm_mfma(const u16* __restrict__ A, const u16* __restrict__ Bt,
                          const float* __restrict__ bias, float* __restrict__ C,
                          int M, int N, int K, int doRelu) {
    __shared__ __align__(16) u16 As[GBM][GBK + 8];   // +8 bf16 = 16B pad
    __shared__ __align__(16) u16 Bs[GBN][GBK + 8];

    int tid = threadIdx.x;
    int lane = tid & 63;
    int wave = tid >> 6;           // 0..3
    int wm = (wave & 1) * 32;
    int wn = (wave >> 1) * 32;
    int rowBase = blockIdx.x * GBM;
    int colBase = blockIdx.y * GBN;

    floatx4 acc[2][2];
#pragma unroll
    for (int i = 0; i < 2; ++i)
#pragma unroll
        for (int j = 0; j < 2; ++j) {
            acc[i][j][0] = 0.f; acc[i][j][1] = 0.f; acc[i][j][2] = 0.f; acc[i][j][3] = 0.f;
        }

    int sr = tid >> 3;             // 0..31
    int sc = (tid & 7) * 8;        // 0..56

    for (int k0 = 0; k0 < K; k0 += GBK) {
#pragma unroll
        for (int h = 0; h < 2; ++h) {
            int r = sr + h * 32;
            int gm = rowBase + r;
            uint4 v = make_uint4(0, 0, 0, 0);
            if (gm < M) v = *(const uint4*)(A + (size_t)gm * K + k0 + sc);
            *(uint4*)&As[r][sc] = v;
            int gn = colBase + r;                     // N is a multiple of 64 -> no guard
            uint4 w = *(const uint4*)(Bt + (size_t)gn * K + k0 + sc);
            *(uint4*)&Bs[r][sc] = w;
        }
        __syncthreads();

        int mrow = lane & 15;
        int kq = (lane >> 4) * 8;
#pragma unroll
        for (int kk = 0; kk < GBK; kk += 32) {
            short8 af[2], bfr[2];
#pragma unroll
            for (int i = 0; i < 2; ++i) af[i] = *(const short8*)&As[wm + i * 16 + mrow][kk + kq];
#pragma unroll
            for (int j = 0; j < 2; ++j) bfr[j] = *(const short8*)&Bs[wn + j * 16 + mrow][kk + kq];
#pragma unroll
            for (int i = 0; i < 2; ++i)
#pragma unroll
                for (int j = 0; j < 2; ++j)
                    acc[i][j] = __builtin_amdgcn_mfma_f32_16x16x32_bf16(af[i], bfr[j], acc[i][j], 0, 0, 0);
        }
        __syncthreads();
    }

    // epilogue: C/D layout col = lane&15, row = (lane>>4)*4 + reg
    int cn0 = colBase + wn + (lane & 15);
    int rq = (lane >> 4) * 4;
#pragma unroll
    for (int i = 0; i < 2; ++i) {
#pragma unroll
        for (int r = 0; r < 4; ++r) {
            int m = rowBase + wm + i * 16 + rq + r;
            if (m >= M) continue;
#pragma unroll
            for (int j = 0; j < 2; ++j) {
                int n = cn0 + j * 16;
                float v = acc[i][j][r] + bias[n];
                if (doRelu) v = fmaxf(v, 0.0f);
                C[(size_t)m * N + n] = v;
            }
        }
    }
}

// ---------------- batchnorm ----------------

#define BN_ROWS 64
__global__ void bn_stats(const float* __restrict__ h, int N, int C,
                         float* __restrict__ sums, float* __restrict__ sumsq) {
    int c = threadIdx.x;
    int r0 = blockIdx.x * BN_ROWS;
    int r1 = min(r0 + BN_ROWS, N);
    float s = 0.f, q = 0.f;
    for (int r = r0; r < r1; ++r) {
        float v = h[(size_t)r * C + c];
        s += v;
        q += v * v;
    }
    atomicAdd(&sums[c], s);
    atomicAdd(&sumsq[c], q);
}

__global__ void bn_final(const float* __restrict__ sums, const float* __restrict__ sumsq,
                         const float* __restrict__ gamma, const float* __restrict__ beta,
                         float* __restrict__ scale, float* __restrict__ shift, int C, float invN) {
    int c = threadIdx.x + blockIdx.x * blockDim.x;
    if (c >= C) return;
    float m = sums[c] * invN;
    float var = sumsq[c] * invN - m * m;
    float sc = gamma[c] / sqrtf(var + BN_EPS);
    scale[c] = sc;
    shift[c] = beta[c] - m * sc;
}

// fp32 -> bf16 slice apply (for BN1 -> A2 slice 0)
__global__ void bn_apply_bf(const float* __restrict__ h, const float* __restrict__ scale,
                            const float* __restrict__ shift, u16* __restrict__ out,
                            int n_elems, int C, int ldo) {
    int i = blockIdx.x * blockDim.x + threadIdx.x;
    if (i >= n_elems) return;
    int n = i / C, c = i - n * C;
    out[(size_t)n * ldo + c] = f2bf(h[i] * scale[c] + shift[c]);
}

// fp32 in-place apply (for BN2)
__global__ void bn_apply(const float* __restrict__ h, const float* __restrict__ scale,
                         const float* __restrict__ shift, float* __restrict__ out,
                         int n_elems, int C, int ldo) {
    int i = blockIdx.x * blockDim.x + threadIdx.x;
    if (i >= n_elems) return;
    int n = i / C, c = i - n * C;
    out[(size_t)n * ldo + c] = h[i] * scale[c] + shift[c];
}

// ---------------- final linear ----------------

__global__ void final_linear(const float* __restrict__ g, const float* __restrict__ Wlin,
                             const float* __restrict__ blin, float* __restrict__ out, int N) {
    __shared__ float Ws[OUT_F * CL2_F];
    __shared__ float bs[OUT_F];
    for (int i = threadIdx.x; i < OUT_F * CL2_F; i += 256) Ws[i] = Wlin[i];
    if (threadIdx.x < OUT_F) bs[threadIdx.x] = blin[threadIdx.x];
    __syncthreads();
    int idx = blockIdx.x * 256 + threadIdx.x;
    if (idx >= N * OUT_F) return;
    int n = idx / OUT_F, o = idx - n * OUT_F;
    const float* gr = g + (size_t)n * CL2_F;
    const float* wr = Ws + o * CL2_F;
    float acc = 0.f;
#pragma unroll 8
    for (int f = 0; f < CL2_F; ++f) acc += gr[f] * wr[f];
    out[idx] = acc + bs[o];
}

// ---------------- host launch ----------------

extern "C" void kernel_launch(void* const* d_in, const int* in_sizes, int n_in,
                              void* d_out, int out_size, void* d_ws, size_t ws_size,
                              hipStream_t stream) {
    const float* x      = (const float*)d_in[0];
    const int*   ei     = (const int*)d_in[1];
    const float* ew     = (const float*)d_in[2];
    const float* W1     = (const float*)d_in[3];   // (4,128,256) -> (512,256)
    const float* b1     = (const float*)d_in[4];
    const float* W2     = (const float*)d_in[5];   // (4,256,128) -> (1024,128)
    const float* b2     = (const float*)d_in[6];
    const float* gamma1 = (const float*)d_in[7];
    const float* beta1  = (const float*)d_in[8];
    const float* gamma2 = (const float*)d_in[9];
    const float* beta2  = (const float*)d_in[10];
    const float* Wlin   = (const float*)d_in[11];
    const float* blin   = (const float*)d_in[12];
    float* out = (float*)d_out;

    const int N = NNODES, E = NEDGES;

    // workspace layout (~67.6 MB, all offsets 16B-aligned)
    char* base = (char*)d_ws;
    u16*   A2     = (u16*)  (base + 0);             // N*1024 bf16 = 40.96 MB
    u16*   A1     = A2;                             // N*512 bf16 (dead before A2 fully written)
    float* h1     = (float*)(base + 40960000);      // N*256 fp32 = 20.48 MB
    float* h2     = h1;                             // N*128 fp32
    u16*   W1t    = (u16*)  (base + 61440000);      // 256*512 bf16
    u16*   W2t    = (u16*)  (base + 61720000);      // 128*1024 bf16
    int*   esrc   = (int*)  (base + 62000000);      // E
    float* ewn    = (float*)(base + 64560000);      // E
    int*   rowptr = (int*)  (base + 67120000);      // N+1
    int*   off    = (int*)  (base + 67210000);      // N
    int*   cnt    = (int*)  (base + 67300000);      // N
    float* deg    = (float*)(base + 67380000);      // N
    float* dis    = (float*)(base + 67460000);      // N
    float* bns    = (float*)(base + 67540000);      // 256
    float* bnq     = bns + 256;
    float* bnscale = bnq + 256;
    float* bnshift = bnscale + 256;

    dim3 blk(256);

    // --- build normalized CSC + weight conversion ---
    hipMemsetAsync(cnt, 0, N * sizeof(int), stream);
    hipMemsetAsync(deg, 0, N * sizeof(float), stream);
    count_deg<<<dim3((E + 255) / 256), blk, 0, stream>>>(ei, ew, deg, cnt, E);
    dis_kernel<<<dim3((N + 255) / 256), blk, 0, stream>>>(deg, dis, N);
    scan_kernel<<<dim3(1), blk, 0, stream>>>(cnt, rowptr, off, N);
    fill_edges<<<dim3((E + 255) / 256), blk, 0, stream>>>(ei, ew, dis, off, esrc, ewn, E);
    conv_w_t<<<dim3((512 * 256 + 255) / 256), blk, 0, stream>>>(W1, W1t, 512, 256);
    conv_w_t<<<dim3((1024 * 128 + 255) / 256), blk, 0, stream>>>(W2, W2t, 1024, 128);

    // --- layer 1: A1 = [Tx0|Tx1|Tx2|Tx3] bf16, F=128, ld=512 ---
    {
        const int F = 128, LD = 512, SH = 4;   // 16 threads/node, 8 feats each
        dim3 gEl((N * F + 255) / 256);
        dim3 gG(((N << SH) + 255) / 256);
        conv_x_bf<<<gEl, blk, 0, stream>>>(x, A1 + 0, N * F, F, LD);
        spmm_gather_bf<<<gG, blk, 0, stream>>>(rowptr, esrc, ewn, A1 + 0,     nullptr, A1 + F,     N, SH, LD, 1.0f);
        spmm_gather_bf<<<gG, blk, 0, stream>>>(rowptr, esrc, ewn, A1 + F,     A1 + 0,  A1 + 2 * F, N, SH, LD, 2.0f);
        spmm_gather_bf<<<gG, blk, 0, stream>>>(rowptr, esrc, ewn, A1 + 2 * F, A1 + F,  A1 + 3 * F, N, SH, LD, 2.0f);
    }

    // --- GEMM1: h1 = relu(A1 @ W1s + b1), M=20000 K=512 N=256 ---
    gemm_mfma<<<dim3((N + GBM - 1) / GBM, CL1_F / GBN), blk, 0, stream>>>(
        A1, W1t, b1, h1, N, CL1_F, 512, 1);

    // --- BN1 -> A2 slice 0 (bf16, ld 1024) ---
    hipMemsetAsync(bns, 0, 2 * 256 * sizeof(float), stream);
    bn_stats<<<dim3((N + BN_ROWS - 1) / BN_ROWS), dim3(CL1_F), 0, stream>>>(h1, N, CL1_F, bns, bnq);
    bn_final<<<dim3(1), dim3(CL1_F), 0, stream>>>(bns, bnq, gamma1, beta1, bnscale, bnshift, CL1_F, 1.0f / N);
    bn_apply_bf<<<dim3((N * CL1_F + 255) / 256), blk, 0, stream>>>(h1, bnscale, bnshift, A2 + 0, N * CL1_F, CL1_F, 1024);

    // --- layer 2: A2 slices bf16, F=256, ld=1024 ---
    {
        const int F = 256, LD = 1024, SH = 5;  // 32 threads/node
        dim3 gG(((N << SH) + 255) / 256);
        spmm_gather_bf<<<gG, blk, 0, stream>>>(rowptr, esrc, ewn, A2 + 0,     nullptr, A2 + F,     N, SH, LD, 1.0f);
        spmm_gather_bf<<<gG, blk, 0, stream>>>(rowptr, esrc, ewn, A2 + F,     A2 + 0,  A2 + 2 * F, N, SH, LD, 2.0f);
        spmm_gather_bf<<<gG, blk, 0, stream>>>(rowptr, esrc, ewn, A2 + 2 * F, A2 + F,  A2 + 3 * F, N, SH, LD, 2.0f);
    }

    // --- GEMM2: h2 = relu(A2 @ W2s + b2), M=20000 K=1024 N=128 ---
    gemm_mfma<<<dim3((N + GBM - 1) / GBM, CL2_F / GBN), blk, 0, stream>>>(
        A2, W2t, b2, h2, N, CL2_F, 1024, 1);

    // --- BN2 in-place on h2 (fp32) ---
    hipMemsetAsync(bns, 0, 2 * 256 * sizeof(float), stream);
    bn_stats<<<dim3((N + BN_ROWS - 1) / BN_ROWS), dim3(CL2_F), 0, stream>>>(h2, N, CL2_F, bns, bnq);
    bn_final<<<dim3(1), dim3(CL2_F), 0, stream>>>(bns, bnq, gamma2, beta2, bnscale, bnshift, CL2_F, 1.0f / N);
    bn_apply<<<dim3((N * CL2_F + 255) / 256), blk, 0, stream>>>(h2, bnscale, bnshift, h2, N * CL2_F, CL2_F, CL2_F);

    // --- final linear ---
    final_linear<<<dim3((N * OUT_F + 255) / 256), blk, 0, stream>>>(h2, Wlin, blin, out, N);
}

// Round 4
// 554.267 us; speedup vs baseline: 18.0203x; 1.0750x over previous
//
#include <hip/hip_runtime.h>
#include <cstdint>
#include <cstddef>

// Problem constants (match reference)
#define NNODES 20000
#define NEDGES 640000
#define IN_F   128
#define CL1_F  256
#define CL2_F  128
#define OUT_F  10
#define BN_EPS 1e-5f
#define NR     8          // atomic-counter replicas

typedef unsigned short u16;

// ---------------- bf16 helpers ----------------

__device__ __forceinline__ u16 f2bf(float f) {
    union { float f; uint32_t i; } v; v.f = f;
    uint32_t r = v.i + 0x7fffu + ((v.i >> 16) & 1u);   // RNE
    return (u16)(r >> 16);
}
__device__ __forceinline__ void bf2x2(uint32_t u, float& lo, float& hi) {
    union { uint32_t i; float f; } a, b;
    a.i = u << 16; b.i = u & 0xffff0000u;
    lo = a.f; hi = b.f;
}
__device__ __forceinline__ uint32_t f2bf2(float lo, float hi) {
    return (uint32_t)f2bf(lo) | ((uint32_t)f2bf(hi) << 16);
}
__device__ __forceinline__ void unpack8(uint4 v, float* o) {
    bf2x2(v.x, o[0], o[1]); bf2x2(v.y, o[2], o[3]);
    bf2x2(v.z, o[4], o[5]); bf2x2(v.w, o[6], o[7]);
}

// ---------------- CSC build (replicated atomics) ----------------

// rep(e) must match between count_deg and fill_edges
__device__ __forceinline__ int erep(int e) { return (e >> 13) & (NR - 1); }

__global__ void count_deg(const int* __restrict__ ei, const float* __restrict__ ew,
                          float* __restrict__ deg8, int* __restrict__ cnt8, int E, int N) {
    int e = blockIdx.x * blockDim.x + threadIdx.x;
    if (e >= E) return;
    int r = ei[e];
    int c = ei[E + e];
    int k = erep(e);
    float w = (r == c) ? 0.0f : ew[e];
    atomicAdd(&cnt8[k * N + c], 1);
    if (w != 0.0f) atomicAdd(&deg8[k * N + r], w);
}

// per-node: total counts, dis = 1/sqrt(deg)
__global__ void sum_replicas(const int* __restrict__ cnt8, const float* __restrict__ deg8,
                             int* __restrict__ tot, float* __restrict__ dis, int N) {
    int i = blockIdx.x * blockDim.x + threadIdx.x;
    if (i >= N) return;
    int t = 0; float d = 0.f;
#pragma unroll
    for (int k = 0; k < NR; ++k) { t += cnt8[k * N + i]; d += deg8[k * N + i]; }
    tot[i] = t;
    dis[i] = (d > 0.0f) ? (1.0f / sqrtf(d)) : 0.0f;
}

// single-block exclusive scan of tot -> rowptr
__global__ void scan_kernel(const int* __restrict__ tot, int* __restrict__ rowptr, int N) {
    __shared__ int sums[256];
    int t = threadIdx.x;
    int per = (N + 255) / 256;
    int s0 = t * per, s1 = min(s0 + per, N);
    int s = 0;
    for (int i = s0; i < s1; ++i) s += tot[i];
    sums[t] = s;
    __syncthreads();
    if (t == 0) {
        int run = 0;
        for (int i = 0; i < 256; ++i) { int v = sums[i]; sums[i] = run; run += v; }
        rowptr[N] = run;
    }
    __syncthreads();
    int run = sums[t];
    for (int i = s0; i < s1; ++i) { rowptr[i] = run; run += tot[i]; }
}

// per-replica fill bases: off8[k][i] = rowptr[i] + sum_{j<k} cnt8[j][i]
__global__ void make_off(const int* __restrict__ rowptr, const int* __restrict__ cnt8,
                         int* __restrict__ off8, int N) {
    int i = blockIdx.x * blockDim.x + threadIdx.x;
    if (i >= N) return;
    int run = rowptr[i];
#pragma unroll
    for (int k = 0; k < NR; ++k) { off8[k * N + i] = run; run += cnt8[k * N + i]; }
}

// scatter edges into CSC order as packed (src, weight_bits)
__global__ void fill_edges(const int* __restrict__ ei, const float* __restrict__ ew,
                           const float* __restrict__ dis, int* __restrict__ off8,
                           int2* __restrict__ epair, int E, int N) {
    int e = blockIdx.x * blockDim.x + threadIdx.x;
    if (e >= E) return;
    int r = ei[e];
    int c = ei[E + e];
    int k = erep(e);
    float w = (r == c) ? 0.0f : ew[e];
    float wn = -(dis[r] * w * dis[c]);   // * (2/lambda_max) = *1
    int pos = atomicAdd(&off8[k * N + c], 1);
    epair[pos] = make_int2(r, __float_as_int(wn));
}

// ---------------- conversions ----------------

__global__ void conv_x_bf(const float* __restrict__ x, u16* __restrict__ dst,
                          int n_elems, int F, int ld) {
    int i = blockIdx.x * blockDim.x + threadIdx.x;
    if (i >= n_elems) return;
    int n = i / F, f = i - n * F;
    dst[(size_t)n * ld + f] = f2bf(x[i]);
}

// both weights, transposed to [NN][KK] bf16, in one launch
__global__ void conv_w_both(const float* __restrict__ W1, u16* __restrict__ W1t,
                            const float* __restrict__ W2, u16* __restrict__ W2t) {
    int i = blockIdx.x * blockDim.x + threadIdx.x;
    const int S1 = 512 * 256;            // W1: K=512, N=256
    const int S2 = 1024 * 128;           // W2: K=1024, N=128
    if (i < S1) {
        int k = i / 256, n = i - k * 256;
        W1t[(size_t)n * 512 + k] = f2bf(W1[i]);
    } else if (i < S1 + S2) {
        int j = i - S1;
        int k = j / 128, n = j - k * 128;
        W2t[(size_t)n * 1024 + k] = f2bf(W2[j]);
    }
}

// ---------------- spmm gather (CSC, bf16 in/out, fp32 accumulate) ----------------
// tout[n] = s * sum_p w[p] * tin[src[p]] - tprev[n]   (tprev==nullptr -> no sub)
__launch_bounds__(256)
__global__ void spmm_gather_bf(const int* __restrict__ rowptr, const int2* __restrict__ epair,
                               const u16* __restrict__ tin, const u16* __restrict__ tprev,
                               u16* __restrict__ tout, int N, int f8shift, int ld, float s) {
    int gid = blockIdx.x * blockDim.x + threadIdx.x;
    int n = gid >> f8shift;
    if (n >= N) return;
    int f = (gid & ((1 << f8shift) - 1)) << 3;
    int p = rowptr[n], pe = rowptr[n + 1];
    float acc[8] = {};
    for (; p + 1 < pe; p += 2) {
        int2 ea = epair[p], eb = epair[p + 1];
        float wa = __int_as_float(ea.y), wb = __int_as_float(eb.y);
        uint4 va = *(const uint4*)(tin + (size_t)ea.x * ld + f);
        uint4 vb = *(const uint4*)(tin + (size_t)eb.x * ld + f);
        float fa[8], fb[8];
        unpack8(va, fa); unpack8(vb, fb);
#pragma unroll
        for (int q = 0; q < 8; ++q) acc[q] += wa * fa[q] + wb * fb[q];
    }
    if (p < pe) {
        int2 ea = epair[p];
        float wa = __int_as_float(ea.y);
        uint4 va = *(const uint4*)(tin + (size_t)ea.x * ld + f);
        float fa[8];
        unpack8(va, fa);
#pragma unroll
        for (int q = 0; q < 8; ++q) acc[q] += wa * fa[q];
    }
    if (tprev) {
        uint4 pv = *(const uint4*)(tprev + (size_t)n * ld + f);
        float fp[8];
        unpack8(pv, fp);
#pragma unroll
        for (int q = 0; q < 8; ++q) acc[q] = s * acc[q] - fp[q];
    } else {
#pragma unroll
        for (int q = 0; q < 8; ++q) acc[q] *= s;
    }
    uint4 o;
    o.x = f2bf2(acc[0], acc[1]);
    o.y = f2bf2(acc[2], acc[3]);
    o.z = f2bf2(acc[4], acc[5]);
    o.w = f2bf2(acc[6], acc[7]);
    *(uint4*)(tout + (size_t)n * ld + f) = o;
}

// ---------------- bf16 MFMA GEMM ----------------
// C[M,N] fp32 = A[M,K] bf16 (lda=K) @ Bt[N,K] bf16 (ldb=K) + bias; relu opt.

typedef __attribute__((ext_vector_type(8))) short short8;
typedef __attribute__((ext_vector_type(4))) float floatx4;

#define GBM 64
#define GBN 64
#define GBK 64

__launch_bounds__(256)
__global__ void gemm_mfma(const u16* __restrict__ A, const u16* __restrict__ Bt,
                          const float* __restrict__ bias, float* __restrict__ C,
                          int M, int N, int K, int doRelu) {
    __shared__ __align__(16) u16 As[GBM][GBK + 8];
    __shared__ __align__(16) u16 Bs[GBN][GBK + 8];

    int tid = threadIdx.x;
    int lane = tid & 63;
    int wave = tid >> 6;
    int wm = (wave & 1) * 32;
    int wn = (wave >> 1) * 32;
    int rowBase = blockIdx.x * GBM;
    int colBase = blockIdx.y * GBN;

    floatx4 acc[2][2];
#pragma unroll
    for (int i = 0; i < 2; ++i)
#pragma unroll
        for (int j = 0; j < 2; ++j) {
            acc[i][j][0] = 0.f; acc[i][j][1] = 0.f; acc[i][j][2] = 0.f; acc[i][j][3] = 0.f;
        }

    int sr = tid >> 3;
    int sc = (tid & 7) * 8;

    for (int k0 = 0; k0 < K; k0 += GBK) {
#pragma unroll
        for (int h = 0; h < 2; ++h) {
            int r = sr + h * 32;
            int gm = rowBase + r;
            uint4 v = make_uint4(0, 0, 0, 0);
            if (gm < M) v = *(const uint4*)(A + (size_t)gm * K + k0 + sc);
            *(uint4*)&As[r][sc] = v;
            int gn = colBase + r;
            uint4 w = *(const uint4*)(Bt + (size_t)gn * K + k0 + sc);
            *(uint4*)&Bs[r][sc] = w;
        }
        __syncthreads();

        int mrow = lane & 15;
        int kq = (lane >> 4) * 8;
#pragma unroll
        for (int kk = 0; kk < GBK; kk += 32) {
            short8 af[2], bfr[2];
#pragma unroll
            for (int i = 0; i < 2; ++i) af[i] = *(const short8*)&As[wm + i * 16 + mrow][kk + kq];
#pragma unroll
            for (int j = 0; j < 2; ++j) bfr[j] = *(const short8*)&Bs[wn + j * 16 + mrow][kk + kq];
#pragma unroll
            for (int i = 0; i < 2; ++i)
#pragma unroll
                for (int j = 0; j < 2; ++j)
                    acc[i][j] = __builtin_amdgcn_mfma_f32_16x16x32_bf16(af[i], bfr[j], acc[i][j], 0, 0, 0);
        }
        __syncthreads();
    }

    int cn0 = colBase + wn + (lane & 15);
    int rq = (lane >> 4) * 4;
#pragma unroll
    for (int i = 0; i < 2; ++i) {
#pragma unroll
        for (int r = 0; r < 4; ++r) {
            int m = rowBase + wm + i * 16 + rq + r;
            if (m >= M) continue;
#pragma unroll
            for (int j = 0; j < 2; ++j) {
                int n = cn0 + j * 16;
                float v = acc[i][j][r] + bias[n];
                if (doRelu) v = fmaxf(v, 0.0f);
                C[(size_t)m * N + n] = v;
            }
        }
    }
}

// ---------------- batchnorm ----------------

#define BN_ROWS 64
__global__ void bn_stats(const float* __restrict__ h, int N, int C,
                         float* __restrict__ sums, float* __restrict__ sumsq) {
    int c = threadIdx.x;
    int r0 = blockIdx.x * BN_ROWS;
    int r1 = min(r0 + BN_ROWS, N);
    float s = 0.f, q = 0.f;
    for (int r = r0; r < r1; ++r) {
        float v = h[(size_t)r * C + c];
        s += v;
        q += v * v;
    }
    atomicAdd(&sums[c], s);
    atomicAdd(&sumsq[c], q);
}

__global__ void bn_final(const float* __restrict__ sums, const float* __restrict__ sumsq,
                         const float* __restrict__ gamma, const float* __restrict__ beta,
                         float* __restrict__ scale, float* __restrict__ shift, int C, float invN) {
    int c = threadIdx.x + blockIdx.x * blockDim.x;
    if (c >= C) return;
    float m = sums[c] * invN;
    float var = sumsq[c] * invN - m * m;
    float sc = gamma[c] / sqrtf(var + BN_EPS);
    scale[c] = sc;
    shift[c] = beta[c] - m * sc;
}

__global__ void bn_apply_bf(const float* __restrict__ h, const float* __restrict__ scale,
                            const float* __restrict__ shift, u16* __restrict__ out,
                            int n_elems, int C, int ldo) {
    int i = blockIdx.x * blockDim.x + threadIdx.x;
    if (i >= n_elems) return;
    int n = i / C, c = i - n * C;
    out[(size_t)n * ldo + c] = f2bf(h[i] * scale[c] + shift[c]);
}

__global__ void bn_apply(const float* __restrict__ h, const float* __restrict__ scale,
                         const float* __restrict__ shift, float* __restrict__ out,
                         int n_elems, int C, int ldo) {
    int i = blockIdx.x * blockDim.x + threadIdx.x;
    if (i >= n_elems) return;
    int n = i / C, c = i - n * C;
    out[(size_t)n * ldo + c] = h[i] * scale[c] + shift[c];
}

// ---------------- final linear ----------------

__global__ void final_linear(const float* __restrict__ g, const float* __restrict__ Wlin,
                             const float* __restrict__ blin, float* __restrict__ out, int N) {
    __shared__ float Ws[OUT_F * CL2_F];
    __shared__ float bs[OUT_F];
    for (int i = threadIdx.x; i < OUT_F * CL2_F; i += 256) Ws[i] = Wlin[i];
    if (threadIdx.x < OUT_F) bs[threadIdx.x] = blin[threadIdx.x];
    __syncthreads();
    int idx = blockIdx.x * 256 + threadIdx.x;
    if (idx >= N * OUT_F) return;
    int n = idx / OUT_F, o = idx - n * OUT_F;
    const float* gr = g + (size_t)n * CL2_F;
    const float* wr = Ws + o * CL2_F;
    float acc = 0.f;
#pragma unroll 8
    for (int f = 0; f < CL2_F; ++f) acc += gr[f] * wr[f];
    out[idx] = acc + bs[o];
}

// ---------------- host launch ----------------

extern "C" void kernel_launch(void* const* d_in, const int* in_sizes, int n_in,
                              void* d_out, int out_size, void* d_ws, size_t ws_size,
                              hipStream_t stream) {
    const float* x      = (const float*)d_in[0];
    const int*   ei     = (const int*)d_in[1];
    const float* ew     = (const float*)d_in[2];
    const float* W1     = (const float*)d_in[3];
    const float* b1     = (const float*)d_in[4];
    const float* W2     = (const float*)d_in[5];
    const float* b2     = (const float*)d_in[6];
    const float* gamma1 = (const float*)d_in[7];
    const float* beta1  = (const float*)d_in[8];
    const float* gamma2 = (const float*)d_in[9];
    const float* beta2  = (const float*)d_in[10];
    const float* Wlin   = (const float*)d_in[11];
    const float* blin   = (const float*)d_in[12];
    float* out = (float*)d_out;

    const int N = NNODES, E = NEDGES;

    // workspace layout (~69.3 MB, 16B-aligned offsets)
    char* base = (char*)d_ws;
    u16*   A2     = (u16*)  (base + 0);             // N*1024 bf16 = 40.96 MB
    u16*   A1     = A2;                             // N*512 bf16 (aliased)
    float* h1     = (float*)(base + 40960000);      // N*256 fp32 = 20.48 MB
    float* h2     = h1;                             // N*128 fp32 (aliased)
    u16*   W1t    = (u16*)  (base + 61440000);      // 256*512 bf16 = 262144 B
    u16*   W2t    = (u16*)  (base + 61702144);      // 128*1024 bf16 = 262144 B
    int2*  epair  = (int2*) (base + 61964288);      // E*8 = 5.12 MB
    int*   rowptr = (int*)  (base + 67084288);      // N+1
    int*   tot    = (int*)  (base + 67164304);      // N
    int*   cnt8   = (int*)  (base + 67244304);      // NR*N = 640000 B
    float* deg8   = (float*)(base + 67884304);      // NR*N = 640000 B (contiguous w/ cnt8)
    int*   off8   = (int*)  (base + 68524304);      // NR*N
    float* dis    = (float*)(base + 69164304);      // N
    float* bns    = (float*)(base + 69244304);      // 256
    float* bnq     = bns + 256;
    float* bnscale = bnq + 256;
    float* bnshift = bnscale + 256;

    dim3 blk(256);

    // --- build normalized CSC (replicated atomics) + weight conversion ---
    hipMemsetAsync(cnt8, 0, 2 * NR * N * sizeof(int), stream);   // cnt8 + deg8
    count_deg<<<dim3((E + 255) / 256), blk, 0, stream>>>(ei, ew, deg8, cnt8, E, N);
    conv_w_both<<<dim3((512 * 256 + 1024 * 128 + 255) / 256), blk, 0, stream>>>(W1, W1t, W2, W2t);
    sum_replicas<<<dim3((N + 255) / 256), blk, 0, stream>>>(cnt8, deg8, tot, dis, N);
    scan_kernel<<<dim3(1), blk, 0, stream>>>(tot, rowptr, N);
    make_off<<<dim3((N + 255) / 256), blk, 0, stream>>>(rowptr, cnt8, off8, N);
    fill_edges<<<dim3((E + 255) / 256), blk, 0, stream>>>(ei, ew, dis, off8, epair, E, N);

    // --- layer 1: A1 = [Tx0|Tx1|Tx2|Tx3] bf16, F=128, ld=512 ---
    {
        const int F = 128, LD = 512, SH = 4;   // 16 threads/node
        dim3 gEl((N * F + 255) / 256);
        dim3 gG(((N << SH) + 255) / 256);
        conv_x_bf<<<gEl, blk, 0, stream>>>(x, A1 + 0, N * F, F, LD);
        spmm_gather_bf<<<gG, blk, 0, stream>>>(rowptr, epair, A1 + 0,     nullptr, A1 + F,     N, SH, LD, 1.0f);
        spmm_gather_bf<<<gG, blk, 0, stream>>>(rowptr, epair, A1 + F,     A1 + 0,  A1 + 2 * F, N, SH, LD, 2.0f);
        spmm_gather_bf<<<gG, blk, 0, stream>>>(rowptr, epair, A1 + 2 * F, A1 + F,  A1 + 3 * F, N, SH, LD, 2.0f);
    }

    // --- GEMM1: h1 = relu(A1 @ W1s + b1), M=20000 K=512 N=256 ---
    gemm_mfma<<<dim3((N + GBM - 1) / GBM, CL1_F / GBN), blk, 0, stream>>>(
        A1, W1t, b1, h1, N, CL1_F, 512, 1);

    // --- BN1 -> A2 slice 0 (bf16, ld 1024) ---
    hipMemsetAsync(bns, 0, 2 * 256 * sizeof(float), stream);
    bn_stats<<<dim3((N + BN_ROWS - 1) / BN_ROWS), dim3(CL1_F), 0, stream>>>(h1, N, CL1_F, bns, bnq);
    bn_final<<<dim3(1), dim3(CL1_F), 0, stream>>>(bns, bnq, gamma1, beta1, bnscale, bnshift, CL1_F, 1.0f / N);
    bn_apply_bf<<<dim3((N * CL1_F + 255) / 256), blk, 0, stream>>>(h1, bnscale, bnshift, A2 + 0, N * CL1_F, CL1_F, 1024);

    // --- layer 2: A2 slices bf16, F=256, ld=1024 ---
    {
        const int F = 256, LD = 1024, SH = 5;  // 32 threads/node
        dim3 gG(((N << SH) + 255) / 256);
        spmm_gather_bf<<<gG, blk, 0, stream>>>(rowptr, epair, A2 + 0,     nullptr, A2 + F,     N, SH, LD, 1.0f);
        spmm_gather_bf<<<gG, blk, 0, stream>>>(rowptr, epair, A2 + F,     A2 + 0,  A2 + 2 * F, N, SH, LD, 2.0f);
        spmm_gather_bf<<<gG, blk, 0, stream>>>(rowptr, epair, A2 + 2 * F, A2 + F,  A2 + 3 * F, N, SH, LD, 2.0f);
    }

    // --- GEMM2: h2 = relu(A2 @ W2s + b2), M=20000 K=1024 N=128 ---
    gemm_mfma<<<dim3((N + GBM - 1) / GBM, CL2_F / GBN), blk, 0, stream>>>(
        A2, W2t, b2, h2, N, CL2_F, 1024, 1);

    // --- BN2 in-place on h2 (fp32) ---
    hipMemsetAsync(bns, 0, 2 * 256 * sizeof(float), stream);
    bn_stats<<<dim3((N + BN_ROWS - 1) / BN_ROWS), dim3(CL2_F), 0, stream>>>(h2, N, CL2_F, bns, bnq);
    bn_final<<<dim3(1), dim3(CL2_F), 0, stream>>>(bns, bnq, gamma2, beta2, bnscale, bnshift, CL2_F, 1.0f / N);
    bn_apply<<<dim3((N * CL2_F + 255) / 256), blk, 0, stream>>>(h2, bnscale, bnshift, h2, N * CL2_F, CL2_F, CL2_F);

    // --- final linear ---
    final_linear<<<dim3((N * OUT_F + 255) / 256), blk, 0, stream>>>(h2, Wlin, blin, out, N);
}

// Round 5
// 511.460 us; speedup vs baseline: 19.5285x; 1.0837x over previous
//
#include <hip/hip_runtime.h>
#include <cstdint>
#include <cstddef>

// Problem constants (match reference)
#define NNODES 20000
#define NEDGES 640000
#define IN_F   128
#define CL1_F  256
#define CL2_F  128
#define OUT_F  10
#define BN_EPS 1e-5f

#define NC     64                 // edge chunks for CSC build
#define CE     (NEDGES / NC)      // 10000 edges per chunk
#define HALFN  10000              // node half-range for LDS histograms

typedef unsigned short u16;

// ---------------- bf16 helpers ----------------

__device__ __forceinline__ float bf2f(u16 u) {
    union { uint32_t i; float f; } v; v.i = ((uint32_t)u) << 16; return v.f;
}
__device__ __forceinline__ u16 f2bf(float f) {
    union { float f; uint32_t i; } v; v.f = f;
    uint32_t r = v.i + 0x7fffu + ((v.i >> 16) & 1u);   // RNE
    return (u16)(r >> 16);
}
__device__ __forceinline__ void bf2x2(uint32_t u, float& lo, float& hi) {
    union { uint32_t i; float f; } a, b;
    a.i = u << 16; b.i = u & 0xffff0000u;
    lo = a.f; hi = b.f;
}
__device__ __forceinline__ uint32_t f2bf2(float lo, float hi) {
    return (uint32_t)f2bf(lo) | ((uint32_t)f2bf(hi) << 16);
}
__device__ __forceinline__ void unpack8(uint4 v, float* o) {
    bf2x2(v.x, o[0], o[1]); bf2x2(v.y, o[2], o[3]);
    bf2x2(v.z, o[4], o[5]); bf2x2(v.w, o[6], o[7]);
}

// ---------------- CSC build: LDS histograms, zero global atomics ----------------

// Per-chunk histogram of dst counts (u16, packed 2/u32) + src-degree sums (float).
// Two node-halves per chunk to stay under 64 KB LDS.
__launch_bounds__(256)
__global__ void hist_kernel(const int* __restrict__ ei, const float* __restrict__ ew,
                            u16* __restrict__ cnt_h, float* __restrict__ deg_h,
                            int E, int N) {
    __shared__ uint32_t scnt[HALFN / 2];   // 20 KB
    __shared__ float    sdeg[HALFN];       // 40 KB
    int chunk = blockIdx.x;
    int e0 = chunk * CE, e1 = e0 + CE;
    for (int half = 0; half < 2; ++half) {
        int lo = half * HALFN;
        for (int i = threadIdx.x; i < HALFN / 2; i += 256) scnt[i] = 0;
        for (int i = threadIdx.x; i < HALFN; i += 256) sdeg[i] = 0.f;
        __syncthreads();
        for (int e = e0 + threadIdx.x; e < e1; e += 256) {
            int r = ei[e];
            int c = ei[E + e];
            float w = (r == c) ? 0.0f : ew[e];
            int ci = c - lo;
            if ((unsigned)ci < HALFN) atomicAdd(&scnt[ci >> 1], 1u << ((ci & 1) * 16));
            int ri = r - lo;
            if ((unsigned)ri < HALFN) atomicAdd(&sdeg[ri], w);
        }
        __syncthreads();
        for (int i = threadIdx.x; i < HALFN; i += 256) {
            cnt_h[(size_t)chunk * N + lo + i] = (u16)((scnt[i >> 1] >> ((i & 1) * 16)) & 0xffffu);
            deg_h[(size_t)chunk * N + lo + i] = sdeg[i];
        }
        __syncthreads();
    }
}

// per-node totals + dis = 1/sqrt(deg); fully coalesced column reduction
__global__ void reduce_dis(const u16* __restrict__ cnt_h, const float* __restrict__ deg_h,
                           int* __restrict__ tot, float* __restrict__ dis, int N) {
    int i = blockIdx.x * blockDim.x + threadIdx.x;
    if (i >= N) return;
    int t = 0; float d = 0.f;
#pragma unroll 8
    for (int c = 0; c < NC; ++c) {
        t += cnt_h[(size_t)c * N + i];
        d += deg_h[(size_t)c * N + i];
    }
    tot[i] = t;
    dis[i] = (d > 0.0f) ? (1.0f / sqrtf(d)) : 0.0f;
}

// single-block exclusive scan of tot -> rowptr
__global__ void scan_kernel(const int* __restrict__ tot, int* __restrict__ rowptr, int N) {
    __shared__ int sums[256];
    int t = threadIdx.x;
    int per = (N + 255) / 256;
    int s0 = t * per, s1 = min(s0 + per, N);
    int s = 0;
    for (int i = s0; i < s1; ++i) s += tot[i];
    sums[t] = s;
    __syncthreads();
    if (t == 0) {
        int run = 0;
        for (int i = 0; i < 256; ++i) { int v = sums[i]; sums[i] = run; run += v; }
        rowptr[N] = run;
    }
    __syncthreads();
    int run = sums[t];
    for (int i = s0; i < s1; ++i) { rowptr[i] = run; run += tot[i]; }
}

// per-(chunk,node) fill base offsets
__global__ void mkbase(const int* __restrict__ rowptr, const u16* __restrict__ cnt_h,
                       int* __restrict__ baseT, int N) {
    int i = blockIdx.x * blockDim.x + threadIdx.x;
    if (i >= N) return;
    int run = rowptr[i];
#pragma unroll 8
    for (int c = 0; c < NC; ++c) {
        baseT[(size_t)c * N + i] = run;
        run += cnt_h[(size_t)c * N + i];
    }
}

// fill CSC: rank within (chunk, node) via LDS atomics, deterministic global slot
__launch_bounds__(256)
__global__ void fill_kernel(const int* __restrict__ ei, const float* __restrict__ ew,
                            const float* __restrict__ dis, const int* __restrict__ baseT,
                            int2* __restrict__ epair, int E, int N) {
    __shared__ uint32_t srank[HALFN / 2];  // 20 KB
    int chunk = blockIdx.x;
    int e0 = chunk * CE, e1 = e0 + CE;
    for (int half = 0; half < 2; ++half) {
        int lo = half * HALFN;
        for (int i = threadIdx.x; i < HALFN / 2; i += 256) srank[i] = 0;
        __syncthreads();
        for (int e = e0 + threadIdx.x; e < e1; e += 256) {
            int r = ei[e];
            int c = ei[E + e];
            int ci = c - lo;
            if ((unsigned)ci < HALFN) {
                float w = (r == c) ? 0.0f : ew[e];
                float wn = -(dis[r] * w * dis[c]);   // * (2/lambda_max) = *1
                int sh = (ci & 1) * 16;
                uint32_t old = atomicAdd(&srank[ci >> 1], 1u << sh);
                int rank = (old >> sh) & 0xffff;
                int pos = baseT[(size_t)chunk * N + c] + rank;
                epair[pos] = make_int2(r, __float_as_int(wn));
            }
        }
        __syncthreads();
    }
}

// ---------------- conversions ----------------

__global__ void conv_x_bf(const float* __restrict__ x, u16* __restrict__ dst,
                          int n_elems, int F, int ld) {
    int i = blockIdx.x * blockDim.x + threadIdx.x;
    if (i >= n_elems) return;
    int n = i / F, f = i - n * F;
    dst[(size_t)n * ld + f] = f2bf(x[i]);
}

// W1 (4,128,256) -> W1t[256][512]  (Bt layout for GEMM1)
// W2 (4,256,128) -> W2t[512][256]  (Bt layout for GEMM2/Clenshaw; out-block k at rows k*128)
__global__ void conv_w_both(const float* __restrict__ W1, u16* __restrict__ W1t,
                            const float* __restrict__ W2, u16* __restrict__ W2t) {
    int i = blockIdx.x * blockDim.x + threadIdx.x;
    const int S1 = 512 * 256;
    const int S2 = 4 * 256 * 128;
    if (i < S1) {
        int k = i / 256, n = i - k * 256;          // k = kc*128+ci
        W1t[(size_t)n * 512 + k] = f2bf(W1[i]);
    } else if (i < S1 + S2) {
        int j = i - S1;
        int kc = j / (256 * 128);
        int rem = j - kc * 256 * 128;
        int ci = rem / 128, co = rem - ci * 128;
        W2t[(size_t)(kc * 128 + co) * 256 + ci] = f2bf(W2[j]);
    }
}

// ---------------- general spmm (CSC gather, F=128, bf16 io, fp32 accum) ----------------
// tout[n] = s * sum_p w[p]*tin[src[p]] + c1*t1[n] + c2*t2[n]  (+bias, relu if flag)
__launch_bounds__(256)
__global__ void spmm_cl(const int* __restrict__ rowptr, const int2* __restrict__ epair,
                        const u16* __restrict__ tin, int ldi,
                        const u16* __restrict__ t1, int ld1, float c1,
                        const u16* __restrict__ t2, int ld2, float c2,
                        u16* __restrict__ tout, int ldo,
                        const float* __restrict__ bias, int doReluBias,
                        int N, float s) {
    int gid = blockIdx.x * blockDim.x + threadIdx.x;
    int n = gid >> 4;
    if (n >= N) return;
    int f = (gid & 15) << 3;
    int p = rowptr[n], pe = rowptr[n + 1];
    float acc[8] = {};
    for (; p + 1 < pe; p += 2) {
        int2 ea = epair[p], eb = epair[p + 1];
        float wa = __int_as_float(ea.y), wb = __int_as_float(eb.y);
        uint4 va = *(const uint4*)(tin + (size_t)ea.x * ldi + f);
        uint4 vb = *(const uint4*)(tin + (size_t)eb.x * ldi + f);
        float fa[8], fb[8];
        unpack8(va, fa); unpack8(vb, fb);
#pragma unroll
        for (int q = 0; q < 8; ++q) acc[q] += wa * fa[q] + wb * fb[q];
    }
    if (p < pe) {
        int2 ea = epair[p];
        float wa = __int_as_float(ea.y);
        uint4 va = *(const uint4*)(tin + (size_t)ea.x * ldi + f);
        float fa[8];
        unpack8(va, fa);
#pragma unroll
        for (int q = 0; q < 8; ++q) acc[q] += wa * fa[q];
    }
#pragma unroll
    for (int q = 0; q < 8; ++q) acc[q] *= s;
    if (t1) {
        uint4 v = *(const uint4*)(t1 + (size_t)n * ld1 + f);
        float fv[8]; unpack8(v, fv);
#pragma unroll
        for (int q = 0; q < 8; ++q) acc[q] += c1 * fv[q];
    }
    if (t2) {
        uint4 v = *(const uint4*)(t2 + (size_t)n * ld2 + f);
        float fv[8]; unpack8(v, fv);
#pragma unroll
        for (int q = 0; q < 8; ++q) acc[q] += c2 * fv[q];
    }
    if (doReluBias) {
#pragma unroll
        for (int q = 0; q < 8; ++q) acc[q] = fmaxf(acc[q] + bias[f + q], 0.0f);
    }
    uint4 o;
    o.x = f2bf2(acc[0], acc[1]);
    o.y = f2bf2(acc[2], acc[3]);
    o.z = f2bf2(acc[4], acc[5]);
    o.w = f2bf2(acc[6], acc[7]);
    *(uint4*)(tout + (size_t)n * ldo + f) = o;
}

// ---------------- bf16 MFMA GEMM ----------------
// mode 0: C fp32 = relu(A@Bt^T + bias);  mode 1: C bf16 = A@Bt^T (no bias/relu)

typedef __attribute__((ext_vector_type(8))) short short8;
typedef __attribute__((ext_vector_type(4))) float floatx4;

#define GBM 64
#define GBN 64
#define GBK 64

__launch_bounds__(256)
__global__ void gemm_mfma(const u16* __restrict__ A, const u16* __restrict__ Bt,
                          const float* __restrict__ bias, void* __restrict__ Cout,
                          int M, int N, int K, int mode) {
    __shared__ __align__(16) u16 As[GBM][GBK + 8];
    __shared__ __align__(16) u16 Bs[GBN][GBK + 8];

    int tid = threadIdx.x;
    int lane = tid & 63;
    int wave = tid >> 6;
    int wm = (wave & 1) * 32;
    int wn = (wave >> 1) * 32;
    int rowBase = blockIdx.x * GBM;
    int colBase = blockIdx.y * GBN;

    floatx4 acc[2][2];
#pragma unroll
    for (int i = 0; i < 2; ++i)
#pragma unroll
        for (int j = 0; j < 2; ++j) {
            acc[i][j][0] = 0.f; acc[i][j][1] = 0.f; acc[i][j][2] = 0.f; acc[i][j][3] = 0.f;
        }

    int sr = tid >> 3;
    int sc = (tid & 7) * 8;

    for (int k0 = 0; k0 < K; k0 += GBK) {
#pragma unroll
        for (int h = 0; h < 2; ++h) {
            int r = sr + h * 32;
            int gm = rowBase + r;
            uint4 v = make_uint4(0, 0, 0, 0);
            if (gm < M) v = *(const uint4*)(A + (size_t)gm * K + k0 + sc);
            *(uint4*)&As[r][sc] = v;
            int gn = colBase + r;
            uint4 w = *(const uint4*)(Bt + (size_t)gn * K + k0 + sc);
            *(uint4*)&Bs[r][sc] = w;
        }
        __syncthreads();

        int mrow = lane & 15;
        int kq = (lane >> 4) * 8;
#pragma unroll
        for (int kk = 0; kk < GBK; kk += 32) {
            short8 af[2], bfr[2];
#pragma unroll
            for (int i = 0; i < 2; ++i) af[i] = *(const short8*)&As[wm + i * 16 + mrow][kk + kq];
#pragma unroll
            for (int j = 0; j < 2; ++j) bfr[j] = *(const short8*)&Bs[wn + j * 16 + mrow][kk + kq];
#pragma unroll
            for (int i = 0; i < 2; ++i)
#pragma unroll
                for (int j = 0; j < 2; ++j)
                    acc[i][j] = __builtin_amdgcn_mfma_f32_16x16x32_bf16(af[i], bfr[j], acc[i][j], 0, 0, 0);
        }
        __syncthreads();
    }

    int cn0 = colBase + wn + (lane & 15);
    int rq = (lane >> 4) * 4;
    float* Cf = (float*)Cout;
    u16*   Cb = (u16*)Cout;
#pragma unroll
    for (int i = 0; i < 2; ++i) {
#pragma unroll
        for (int r = 0; r < 4; ++r) {
            int m = rowBase + wm + i * 16 + rq + r;
            if (m >= M) continue;
#pragma unroll
            for (int j = 0; j < 2; ++j) {
                int n = cn0 + j * 16;
                float v = acc[i][j][r];
                if (mode == 0) {
                    v = fmaxf(v + bias[n], 0.0f);
                    Cf[(size_t)m * N + n] = v;
                } else {
                    Cb[(size_t)m * N + n] = f2bf(v);
                }
            }
        }
    }
}

// ---------------- batchnorm ----------------

#define BN_ROWS 64
__global__ void bn_stats(const float* __restrict__ h, int N, int C,
                         float* __restrict__ sums, float* __restrict__ sumsq) {
    int c = threadIdx.x;
    int r0 = blockIdx.x * BN_ROWS;
    int r1 = min(r0 + BN_ROWS, N);
    float s = 0.f, q = 0.f;
    for (int r = r0; r < r1; ++r) {
        float v = h[(size_t)r * C + c];
        s += v;
        q += v * v;
    }
    atomicAdd(&sums[c], s);
    atomicAdd(&sumsq[c], q);
}

__global__ void bn_stats_bf(const u16* __restrict__ h, int N, int C,
                            float* __restrict__ sums, float* __restrict__ sumsq) {
    int c = threadIdx.x;
    int r0 = blockIdx.x * BN_ROWS;
    int r1 = min(r0 + BN_ROWS, N);
    float s = 0.f, q = 0.f;
    for (int r = r0; r < r1; ++r) {
        float v = bf2f(h[(size_t)r * C + c]);
        s += v;
        q += v * v;
    }
    atomicAdd(&sums[c], s);
    atomicAdd(&sumsq[c], q);
}

__global__ void bn_final(const float* __restrict__ sums, const float* __restrict__ sumsq,
                         const float* __restrict__ gamma, const float* __restrict__ beta,
                         float* __restrict__ scale, float* __restrict__ shift, int C, float invN) {
    int c = threadIdx.x + blockIdx.x * blockDim.x;
    if (c >= C) return;
    float m = sums[c] * invN;
    float var = sumsq[c] * invN - m * m;
    float sc = gamma[c] / sqrtf(var + BN_EPS);
    scale[c] = sc;
    shift[c] = beta[c] - m * sc;
}

// fp32 in -> bf16 out
__global__ void bn_apply_bf(const float* __restrict__ h, const float* __restrict__ scale,
                            const float* __restrict__ shift, u16* __restrict__ out,
                            int n_elems, int C) {
    int i = blockIdx.x * blockDim.x + threadIdx.x;
    if (i >= n_elems) return;
    int c = i % C;
    out[i] = f2bf(h[i] * scale[c] + shift[c]);
}

// bf16 in -> fp32 out
__global__ void bn_apply_bf2f(const u16* __restrict__ h, const float* __restrict__ scale,
                              const float* __restrict__ shift, float* __restrict__ out,
                              int n_elems, int C) {
    int i = blockIdx.x * blockDim.x + threadIdx.x;
    if (i >= n_elems) return;
    int c = i % C;
    out[i] = bf2f(h[i]) * scale[c] + shift[c];
}

// ---------------- final linear ----------------

__global__ void final_linear(const float* __restrict__ g, const float* __restrict__ Wlin,
                             const float* __restrict__ blin, float* __restrict__ out, int N) {
    __shared__ float Ws[OUT_F * CL2_F];
    __shared__ float bs[OUT_F];
    for (int i = threadIdx.x; i < OUT_F * CL2_F; i += 256) Ws[i] = Wlin[i];
    if (threadIdx.x < OUT_F) bs[threadIdx.x] = blin[threadIdx.x];
    __syncthreads();
    int idx = blockIdx.x * 256 + threadIdx.x;
    if (idx >= N * OUT_F) return;
    int n = idx / OUT_F, o = idx - n * OUT_F;
    const float* gr = g + (size_t)n * CL2_F;
    const float* wr = Ws + o * CL2_F;
    float acc = 0.f;
#pragma unroll 8
    for (int f = 0; f < CL2_F; ++f) acc += gr[f] * wr[f];
    out[idx] = acc + bs[o];
}

// ---------------- host launch ----------------

extern "C" void kernel_launch(void* const* d_in, const int* in_sizes, int n_in,
                              void* d_out, int out_size, void* d_ws, size_t ws_size,
                              hipStream_t stream) {
    const float* x      = (const float*)d_in[0];
    const int*   ei     = (const int*)d_in[1];
    const float* ew     = (const float*)d_in[2];
    const float* W1     = (const float*)d_in[3];
    const float* b1     = (const float*)d_in[4];
    const float* W2     = (const float*)d_in[5];
    const float* b2     = (const float*)d_in[6];
    const float* gamma1 = (const float*)d_in[7];
    const float* beta1  = (const float*)d_in[8];
    const float* gamma2 = (const float*)d_in[9];
    const float* beta2  = (const float*)d_in[10];
    const float* Wlin   = (const float*)d_in[11];
    const float* blin   = (const float*)d_in[12];
    float* out = (float*)d_out;

    const int N = NNODES, E = NEDGES;

    // workspace layout (~85.3 MB, 16B-aligned)
    char* base = (char*)d_ws;
    u16*   A1     = (u16*)  (base + 0);             // N*512 bf16 = 20.48 MB (layer-1 Tx)
    u16*   Hc     = A1;                             // N*512 bf16 (aliased; A1 dead after GEMM1)
    float* h1     = (float*)(base + 20480000);      // N*256 fp32 = 20.48 MB
    float* h2     = h1;                             // N*128 fp32 (aliased; h1 dead after BN1)
    u16*   hbn    = (u16*)  (base + 40960000);      // N*256 bf16 = 10.24 MB
    u16*   bb2    = (u16*)  (base + 51200000);      // N*128 bf16 = 5.12 MB
    u16*   bb1    = (u16*)  (base + 56320000);      // N*128 bf16
    u16*   pbuf   = (u16*)  (base + 61440000);      // N*128 bf16
    u16*   W1t    = (u16*)  (base + 66560000);      // 256*512 bf16
    u16*   W2t    = (u16*)  (base + 66822144);      // 512*256 bf16
    int2*  epair  = (int2*) (base + 67084288);      // E*8 = 5.12 MB
    u16*   cnt_h  = (u16*)  (base + 72204288);      // NC*N u16 = 2.56 MB
    float* deg_h  = (float*)(base + 74764288);      // NC*N f32 = 5.12 MB
    int*   baseT  = (int*)  (base + 79884288);      // NC*N i32 = 5.12 MB
    int*   rowptr = (int*)  (base + 85004288);      // N+1
    int*   tot    = (int*)  (base + 85084304);      // N
    float* dis    = (float*)(base + 85164304);      // N
    float* bns    = (float*)(base + 85244304);      // 256
    float* bnq     = bns + 256;
    float* bnscale = bnq + 256;
    float* bnshift = bnscale + 256;

    dim3 blk(256);

    // --- CSC build (LDS histograms; no global atomics) + weight conversion ---
    hist_kernel<<<dim3(NC), blk, 0, stream>>>(ei, ew, cnt_h, deg_h, E, N);
    conv_w_both<<<dim3((512 * 256 + 4 * 256 * 128 + 255) / 256), blk, 0, stream>>>(W1, W1t, W2, W2t);
    reduce_dis<<<dim3((N + 255) / 256), blk, 0, stream>>>(cnt_h, deg_h, tot, dis, N);
    scan_kernel<<<dim3(1), blk, 0, stream>>>(tot, rowptr, N);
    mkbase<<<dim3((N + 255) / 256), blk, 0, stream>>>(rowptr, cnt_h, baseT, N);
    fill_kernel<<<dim3(NC), blk, 0, stream>>>(ei, ew, dis, baseT, epair, E, N);

    dim3 gS(((N << 4) + 255) / 256);   // spmm grid: 16 threads/node

    // --- layer 1: A1 = [x|T1|T2|T3] bf16, ld 512 (forward recursion) ---
    conv_x_bf<<<dim3((N * 128 + 255) / 256), blk, 0, stream>>>(x, A1, N * 128, 128, 512);
    spmm_cl<<<gS, blk, 0, stream>>>(rowptr, epair, A1 + 0,   512, nullptr,  512, 0.f,
                                    nullptr, 512, 0.f, A1 + 128, 512, nullptr, 0, N, 1.0f);
    spmm_cl<<<gS, blk, 0, stream>>>(rowptr, epair, A1 + 128, 512, A1 + 0,   512, -1.f,
                                    nullptr, 512, 0.f, A1 + 256, 512, nullptr, 0, N, 2.0f);
    spmm_cl<<<gS, blk, 0, stream>>>(rowptr, epair, A1 + 256, 512, A1 + 128, 512, -1.f,
                                    nullptr, 512, 0.f, A1 + 384, 512, nullptr, 0, N, 2.0f);

    // --- GEMM1: h1 = relu(A1 @ W1 + b1)  [M=20000, N=256, K=512] fp32 out ---
    gemm_mfma<<<dim3((N + GBM - 1) / GBM, CL1_F / GBN), blk, 0, stream>>>(
        A1, W1t, b1, h1, N, CL1_F, 512, 0);

    // --- BN1: stats(h1) -> apply -> hbn bf16 (N x 256) ---
    hipMemsetAsync(bns, 0, 2 * 256 * sizeof(float), stream);
    bn_stats<<<dim3((N + BN_ROWS - 1) / BN_ROWS), dim3(CL1_F), 0, stream>>>(h1, N, CL1_F, bns, bnq);
    bn_final<<<dim3(1), dim3(CL1_F), 0, stream>>>(bns, bnq, gamma1, beta1, bnscale, bnshift, CL1_F, 1.0f / N);
    bn_apply_bf<<<dim3((N * CL1_F + 255) / 256), blk, 0, stream>>>(h1, bnscale, bnshift, hbn, N * CL1_F, CL1_F);

    // --- GEMM2: Hc = hbn @ Wcat  [M=20000, N=512, K=256] bf16 out (S_k at Hc + k*128) ---
    gemm_mfma<<<dim3((N + GBM - 1) / GBM, 512 / GBN), blk, 0, stream>>>(
        hbn, W2t, nullptr, Hc, N, 512, 256, 1);

    // --- layer 2 via Clenshaw: all spmms on F=128 ---
    // b2 = 2 L S3 + S2
    spmm_cl<<<gS, blk, 0, stream>>>(rowptr, epair, Hc + 384, 512, Hc + 256, 512, 1.f,
                                    nullptr, 512, 0.f, bb2, 128, nullptr, 0, N, 2.0f);
    // b1 = 2 L b2 - b3 + S1
    spmm_cl<<<gS, blk, 0, stream>>>(rowptr, epair, bb2, 128, Hc + 384, 512, -1.f,
                                    Hc + 128, 512, 1.f, bb1, 128, nullptr, 0, N, 2.0f);
    // p = relu(L b1 - b2 + S0 + bias)
    spmm_cl<<<gS, blk, 0, stream>>>(rowptr, epair, bb1, 128, bb2, 128, -1.f,
                                    Hc + 0, 512, 1.f, pbuf, 128, b2, 1, N, 1.0f);

    // --- BN2: stats(pbuf bf16) -> apply -> h2 fp32 (N x 128) ---
    hipMemsetAsync(bns, 0, 2 * 256 * sizeof(float), stream);
    bn_stats_bf<<<dim3((N + BN_ROWS - 1) / BN_ROWS), dim3(CL2_F), 0, stream>>>(pbuf, N, CL2_F, bns, bnq);
    bn_final<<<dim3(1), dim3(CL2_F), 0, stream>>>(bns, bnq, gamma2, beta2, bnscale, bnshift, CL2_F, 1.0f / N);
    bn_apply_bf2f<<<dim3((N * CL2_F + 255) / 256), blk, 0, stream>>>(pbuf, bnscale, bnshift, h2, N * CL2_F, CL2_F);

    // --- final linear ---
    final_linear<<<dim3((N * OUT_F + 255) / 256), blk, 0, stream>>>(h2, Wlin, blin, out, N);
}

// Round 6
// 477.638 us; speedup vs baseline: 20.9113x; 1.0708x over previous
//
#include <hip/hip_runtime.h>
#include <cstdint>
#include <cstddef>

// Problem constants (match reference)
#define NNODES 20000
#define NEDGES 640000
#define IN_F   128
#define CL1_F  256
#define CL2_F  128
#define OUT_F  10
#define BN_EPS 1e-5f

#define NC     256                // edge chunks for cnt/fill (2500 edges each)
#define CE     (NEDGES / NC)
#define ND     128                // edge chunks for deg (5000 edges each)
#define DE     (NEDGES / ND)
#define HALFN  10000              // node half-range (deg_hist only)

typedef unsigned short u16;

// ---------------- bf16 helpers ----------------

__device__ __forceinline__ float bf2f(u16 u) {
    union { uint32_t i; float f; } v; v.i = ((uint32_t)u) << 16; return v.f;
}
__device__ __forceinline__ u16 f2bf(float f) {
    union { float f; uint32_t i; } v; v.f = f;
    uint32_t r = v.i + 0x7fffu + ((v.i >> 16) & 1u);   // RNE
    return (u16)(r >> 16);
}
__device__ __forceinline__ void bf2x2(uint32_t u, float& lo, float& hi) {
    union { uint32_t i; float f; } a, b;
    a.i = u << 16; b.i = u & 0xffff0000u;
    lo = a.f; hi = b.f;
}
__device__ __forceinline__ uint32_t f2bf2(float lo, float hi) {
    return (uint32_t)f2bf(lo) | ((uint32_t)f2bf(hi) << 16);
}
__device__ __forceinline__ void unpack8(uint4 v, float* o) {
    bf2x2(v.x, o[0], o[1]); bf2x2(v.y, o[2], o[3]);
    bf2x2(v.z, o[4], o[5]); bf2x2(v.w, o[6], o[7]);
}

// ---------------- CSC build: full-parallel LDS histograms ----------------

// per-chunk dst-count histogram, full node range, packed u16 (40 KB LDS)
__launch_bounds__(256)
__global__ void cnt_hist(const int* __restrict__ ei, u16* __restrict__ cnt_h, int E, int N) {
    __shared__ uint32_t scnt[NNODES / 2];   // 40 KB
    int chunk = blockIdx.x;
    int e0 = chunk * CE, e1 = e0 + CE;
    for (int i = threadIdx.x; i < NNODES / 2; i += 256) scnt[i] = 0;
    __syncthreads();
    for (int e = e0 + threadIdx.x; e < e1; e += 256) {
        int c = ei[E + e];
        atomicAdd(&scnt[c >> 1], 1u << ((c & 1) * 16));
    }
    __syncthreads();
    for (int i = threadIdx.x; i < N; i += 256)
        cnt_h[(size_t)chunk * N + i] = (u16)((scnt[i >> 1] >> ((i & 1) * 16)) & 0xffffu);
}

// per-block src-degree partial sums (float, two node halves, 40 KB LDS)
__launch_bounds__(256)
__global__ void deg_hist(const int* __restrict__ ei, const float* __restrict__ ew,
                         float* __restrict__ deg_p, int E, int N) {
    __shared__ float sdeg[HALFN];           // 40 KB
    int b = blockIdx.x;
    int e0 = b * DE, e1 = e0 + DE;
    for (int half = 0; half < 2; ++half) {
        int lo = half * HALFN;
        for (int i = threadIdx.x; i < HALFN; i += 256) sdeg[i] = 0.f;
        __syncthreads();
        for (int e = e0 + threadIdx.x; e < e1; e += 256) {
            int r = ei[e];
            int ri = r - lo;
            if ((unsigned)ri < HALFN) {
                int c = ei[E + e];
                float w = (r == c) ? 0.0f : ew[e];
                atomicAdd(&sdeg[ri], w);
            }
        }
        __syncthreads();
        for (int i = threadIdx.x; i < HALFN; i += 256)
            deg_p[(size_t)b * N + lo + i] = sdeg[i];
        __syncthreads();
    }
}

// per-node totals + dis = 1/sqrt(deg)
__global__ void reduce_dis(const u16* __restrict__ cnt_h, const float* __restrict__ deg_p,
                           int* __restrict__ tot, float* __restrict__ dis, int N) {
    int i = blockIdx.x * blockDim.x + threadIdx.x;
    if (i >= N) return;
    int t = 0;
#pragma unroll 8
    for (int c = 0; c < NC; ++c) t += cnt_h[(size_t)c * N + i];
    float d = 0.f;
#pragma unroll 8
    for (int b = 0; b < ND; ++b) d += deg_p[(size_t)b * N + i];
    tot[i] = t;
    dis[i] = (d > 0.0f) ? (1.0f / sqrtf(d)) : 0.0f;
}

// single-block exclusive scan of tot -> rowptr
__global__ void scan_kernel(const int* __restrict__ tot, int* __restrict__ rowptr, int N) {
    __shared__ int sums[256];
    int t = threadIdx.x;
    int per = (N + 255) / 256;
    int s0 = t * per, s1 = min(s0 + per, N);
    int s = 0;
    for (int i = s0; i < s1; ++i) s += tot[i];
    sums[t] = s;
    __syncthreads();
    if (t == 0) {
        int run = 0;
        for (int i = 0; i < 256; ++i) { int v = sums[i]; sums[i] = run; run += v; }
        rowptr[N] = run;
    }
    __syncthreads();
    int run = sums[t];
    for (int i = s0; i < s1; ++i) { rowptr[i] = run; run += tot[i]; }
}

// per-(chunk,node) fill base offsets
__global__ void mkbase(const int* __restrict__ rowptr, const u16* __restrict__ cnt_h,
                       int* __restrict__ baseT, int N) {
    int i = blockIdx.x * blockDim.x + threadIdx.x;
    if (i >= N) return;
    int run = rowptr[i];
#pragma unroll 8
    for (int c = 0; c < NC; ++c) {
        baseT[(size_t)c * N + i] = run;
        run += cnt_h[(size_t)c * N + i];
    }
}

// fill CSC: rank within (chunk,node) via full-range LDS atomics, single pass
__launch_bounds__(256)
__global__ void fill_kernel(const int* __restrict__ ei, const float* __restrict__ ew,
                            const float* __restrict__ dis, const int* __restrict__ baseT,
                            int2* __restrict__ epair, int E, int N) {
    __shared__ uint32_t srank[NNODES / 2];  // 40 KB
    int chunk = blockIdx.x;
    int e0 = chunk * CE, e1 = e0 + CE;
    for (int i = threadIdx.x; i < NNODES / 2; i += 256) srank[i] = 0;
    __syncthreads();
    for (int e = e0 + threadIdx.x; e < e1; e += 256) {
        int r = ei[e];
        int c = ei[E + e];
        float w = (r == c) ? 0.0f : ew[e];
        float wn = -(dis[r] * w * dis[c]);   // * (2/lambda_max) = *1
        int sh = (c & 1) * 16;
        uint32_t old = atomicAdd(&srank[c >> 1], 1u << sh);
        int rank = (old >> sh) & 0xffff;
        int pos = baseT[(size_t)chunk * N + c] + rank;
        epair[pos] = make_int2(r, __float_as_int(wn));
    }
}

// ---------------- conversions ----------------

__global__ void conv_x_bf(const float* __restrict__ x, u16* __restrict__ dst,
                          int n_elems, int F, int ld) {
    int i = blockIdx.x * blockDim.x + threadIdx.x;
    if (i >= n_elems) return;
    int n = i / F, f = i - n * F;
    dst[(size_t)n * ld + f] = f2bf(x[i]);
}

// W1 (4,128,256) -> W1t[256][512];  W2 (4,256,128) -> W2t[512][256]
__global__ void conv_w_both(const float* __restrict__ W1, u16* __restrict__ W1t,
                            const float* __restrict__ W2, u16* __restrict__ W2t) {
    int i = blockIdx.x * blockDim.x + threadIdx.x;
    const int S1 = 512 * 256;
    const int S2 = 4 * 256 * 128;
    if (i < S1) {
        int k = i / 256, n = i - k * 256;
        W1t[(size_t)n * 512 + k] = f2bf(W1[i]);
    } else if (i < S1 + S2) {
        int j = i - S1;
        int kc = j / (256 * 128);
        int rem = j - kc * 256 * 128;
        int ci = rem / 128, co = rem - ci * 128;
        W2t[(size_t)(kc * 128 + co) * 256 + ci] = f2bf(W2[j]);
    }
}

// ---------------- general spmm (CSC gather, F=128, bf16 io, fp32 accum) ----------------
// tout[n] = s * sum_p w[p]*tin[src[p]] + c1*t1[n] + c2*t2[n]  (+bias, relu if flag)
__launch_bounds__(256)
__global__ void spmm_cl(const int* __restrict__ rowptr, const int2* __restrict__ epair,
                        const u16* __restrict__ tin, int ldi,
                        const u16* __restrict__ t1, int ld1, float c1,
                        const u16* __restrict__ t2, int ld2, float c2,
                        u16* __restrict__ tout, int ldo,
                        const float* __restrict__ bias, int doReluBias,
                        int N, float s) {
    int gid = blockIdx.x * blockDim.x + threadIdx.x;
    int n = gid >> 4;
    if (n >= N) return;
    int f = (gid & 15) << 3;
    int p = rowptr[n], pe = rowptr[n + 1];
    float acc[8] = {};
    for (; p + 1 < pe; p += 2) {
        int2 ea = epair[p], eb = epair[p + 1];
        float wa = __int_as_float(ea.y), wb = __int_as_float(eb.y);
        uint4 va = *(const uint4*)(tin + (size_t)ea.x * ldi + f);
        uint4 vb = *(const uint4*)(tin + (size_t)eb.x * ldi + f);
        float fa[8], fb[8];
        unpack8(va, fa); unpack8(vb, fb);
#pragma unroll
        for (int q = 0; q < 8; ++q) acc[q] += wa * fa[q] + wb * fb[q];
    }
    if (p < pe) {
        int2 ea = epair[p];
        float wa = __int_as_float(ea.y);
        uint4 va = *(const uint4*)(tin + (size_t)ea.x * ldi + f);
        float fa[8];
        unpack8(va, fa);
#pragma unroll
        for (int q = 0; q < 8; ++q) acc[q] += wa * fa[q];
    }
#pragma unroll
    for (int q = 0; q < 8; ++q) acc[q] *= s;
    if (t1) {
        uint4 v = *(const uint4*)(t1 + (size_t)n * ld1 + f);
        float fv[8]; unpack8(v, fv);
#pragma unroll
        for (int q = 0; q < 8; ++q) acc[q] += c1 * fv[q];
    }
    if (t2) {
        uint4 v = *(const uint4*)(t2 + (size_t)n * ld2 + f);
        float fv[8]; unpack8(v, fv);
#pragma unroll
        for (int q = 0; q < 8; ++q) acc[q] += c2 * fv[q];
    }
    if (doReluBias) {
#pragma unroll
        for (int q = 0; q < 8; ++q) acc[q] = fmaxf(acc[q] + bias[f + q], 0.0f);
    }
    uint4 o;
    o.x = f2bf2(acc[0], acc[1]);
    o.y = f2bf2(acc[2], acc[3]);
    o.z = f2bf2(acc[4], acc[5]);
    o.w = f2bf2(acc[6], acc[7]);
    *(uint4*)(tout + (size_t)n * ldo + f) = o;
}

// ---------------- bf16 MFMA GEMM ----------------
// mode 0: C fp32 = relu(A@Bt^T + bias);  mode 1: C bf16 = A@Bt^T

typedef __attribute__((ext_vector_type(8))) short short8;
typedef __attribute__((ext_vector_type(4))) float floatx4;

#define GBM 64
#define GBN 64
#define GBK 64

__launch_bounds__(256)
__global__ void gemm_mfma(const u16* __restrict__ A, const u16* __restrict__ Bt,
                          const float* __restrict__ bias, void* __restrict__ Cout,
                          int M, int N, int K, int mode) {
    __shared__ __align__(16) u16 As[GBM][GBK + 8];
    __shared__ __align__(16) u16 Bs[GBN][GBK + 8];

    int tid = threadIdx.x;
    int lane = tid & 63;
    int wave = tid >> 6;
    int wm = (wave & 1) * 32;
    int wn = (wave >> 1) * 32;
    int rowBase = blockIdx.x * GBM;
    int colBase = blockIdx.y * GBN;

    floatx4 acc[2][2];
#pragma unroll
    for (int i = 0; i < 2; ++i)
#pragma unroll
        for (int j = 0; j < 2; ++j) {
            acc[i][j][0] = 0.f; acc[i][j][1] = 0.f; acc[i][j][2] = 0.f; acc[i][j][3] = 0.f;
        }

    int sr = tid >> 3;
    int sc = (tid & 7) * 8;

    for (int k0 = 0; k0 < K; k0 += GBK) {
#pragma unroll
        for (int h = 0; h < 2; ++h) {
            int r = sr + h * 32;
            int gm = rowBase + r;
            uint4 v = make_uint4(0, 0, 0, 0);
            if (gm < M) v = *(const uint4*)(A + (size_t)gm * K + k0 + sc);
            *(uint4*)&As[r][sc] = v;
            int gn = colBase + r;
            uint4 w = *(const uint4*)(Bt + (size_t)gn * K + k0 + sc);
            *(uint4*)&Bs[r][sc] = w;
        }
        __syncthreads();

        int mrow = lane & 15;
        int kq = (lane >> 4) * 8;
#pragma unroll
        for (int kk = 0; kk < GBK; kk += 32) {
            short8 af[2], bfr[2];
#pragma unroll
            for (int i = 0; i < 2; ++i) af[i] = *(const short8*)&As[wm + i * 16 + mrow][kk + kq];
#pragma unroll
            for (int j = 0; j < 2; ++j) bfr[j] = *(const short8*)&Bs[wn + j * 16 + mrow][kk + kq];
#pragma unroll
            for (int i = 0; i < 2; ++i)
#pragma unroll
                for (int j = 0; j < 2; ++j)
                    acc[i][j] = __builtin_amdgcn_mfma_f32_16x16x32_bf16(af[i], bfr[j], acc[i][j], 0, 0, 0);
        }
        __syncthreads();
    }

    int cn0 = colBase + wn + (lane & 15);
    int rq = (lane >> 4) * 4;
    float* Cf = (float*)Cout;
    u16*   Cb = (u16*)Cout;
#pragma unroll
    for (int i = 0; i < 2; ++i) {
#pragma unroll
        for (int r = 0; r < 4; ++r) {
            int m = rowBase + wm + i * 16 + rq + r;
            if (m >= M) continue;
#pragma unroll
            for (int j = 0; j < 2; ++j) {
                int n = cn0 + j * 16;
                float v = acc[i][j][r];
                if (mode == 0) {
                    v = fmaxf(v + bias[n], 0.0f);
                    Cf[(size_t)m * N + n] = v;
                } else {
                    Cb[(size_t)m * N + n] = f2bf(v);
                }
            }
        }
    }
}

// ---------------- batchnorm ----------------

#define BN_ROWS 64
__global__ void bn_stats(const float* __restrict__ h, int N, int C,
                         float* __restrict__ sums, float* __restrict__ sumsq) {
    int c = threadIdx.x;
    int r0 = blockIdx.x * BN_ROWS;
    int r1 = min(r0 + BN_ROWS, N);
    float s = 0.f, q = 0.f;
    for (int r = r0; r < r1; ++r) {
        float v = h[(size_t)r * C + c];
        s += v;
        q += v * v;
    }
    atomicAdd(&sums[c], s);
    atomicAdd(&sumsq[c], q);
}

__global__ void bn_stats_bf(const u16* __restrict__ h, int N, int C,
                            float* __restrict__ sums, float* __restrict__ sumsq) {
    int c = threadIdx.x;
    int r0 = blockIdx.x * BN_ROWS;
    int r1 = min(r0 + BN_ROWS, N);
    float s = 0.f, q = 0.f;
    for (int r = r0; r < r1; ++r) {
        float v = bf2f(h[(size_t)r * C + c]);
        s += v;
        q += v * v;
    }
    atomicAdd(&sums[c], s);
    atomicAdd(&sumsq[c], q);
}

__global__ void bn_final(const float* __restrict__ sums, const float* __restrict__ sumsq,
                         const float* __restrict__ gamma, const float* __restrict__ beta,
                         float* __restrict__ scale, float* __restrict__ shift, int C, float invN) {
    int c = threadIdx.x + blockIdx.x * blockDim.x;
    if (c >= C) return;
    float m = sums[c] * invN;
    float var = sumsq[c] * invN - m * m;
    float sc = gamma[c] / sqrtf(var + BN_EPS);
    scale[c] = sc;
    shift[c] = beta[c] - m * sc;
}

__global__ void bn_apply_bf(const float* __restrict__ h, const float* __restrict__ scale,
                            const float* __restrict__ shift, u16* __restrict__ out,
                            int n_elems, int C) {
    int i = blockIdx.x * blockDim.x + threadIdx.x;
    if (i >= n_elems) return;
    int c = i % C;
    out[i] = f2bf(h[i] * scale[c] + shift[c]);
}

__global__ void bn_apply_bf2f(const u16* __restrict__ h, const float* __restrict__ scale,
                              const float* __restrict__ shift, float* __restrict__ out,
                              int n_elems, int C) {
    int i = blockIdx.x * blockDim.x + threadIdx.x;
    if (i >= n_elems) return;
    int c = i % C;
    out[i] = bf2f(h[i]) * scale[c] + shift[c];
}

// ---------------- final linear ----------------

__global__ void final_linear(const float* __restrict__ g, const float* __restrict__ Wlin,
                             const float* __restrict__ blin, float* __restrict__ out, int N) {
    __shared__ float Ws[OUT_F * CL2_F];
    __shared__ float bs[OUT_F];
    for (int i = threadIdx.x; i < OUT_F * CL2_F; i += 256) Ws[i] = Wlin[i];
    if (threadIdx.x < OUT_F) bs[threadIdx.x] = blin[threadIdx.x];
    __syncthreads();
    int idx = blockIdx.x * 256 + threadIdx.x;
    if (idx >= N * OUT_F) return;
    int n = idx / OUT_F, o = idx - n * OUT_F;
    const float* gr = g + (size_t)n * CL2_F;
    const float* wr = Ws + o * CL2_F;
    float acc = 0.f;
#pragma unroll 8
    for (int f = 0; f < CL2_F; ++f) acc += gr[f] * wr[f];
    out[idx] = acc + bs[o];
}

// ---------------- host launch ----------------

extern "C" void kernel_launch(void* const* d_in, const int* in_sizes, int n_in,
                              void* d_out, int out_size, void* d_ws, size_t ws_size,
                              hipStream_t stream) {
    const float* x      = (const float*)d_in[0];
    const int*   ei     = (const int*)d_in[1];
    const float* ew     = (const float*)d_in[2];
    const float* W1     = (const float*)d_in[3];
    const float* b1     = (const float*)d_in[4];
    const float* W2     = (const float*)d_in[5];
    const float* b2     = (const float*)d_in[6];
    const float* gamma1 = (const float*)d_in[7];
    const float* beta1  = (const float*)d_in[8];
    const float* gamma2 = (const float*)d_in[9];
    const float* beta2  = (const float*)d_in[10];
    const float* Wlin   = (const float*)d_in[11];
    const float* blin   = (const float*)d_in[12];
    float* out = (float*)d_out;

    const int N = NNODES, E = NEDGES;

    // workspace (~72.5 MB). The CSC-build tables alias the 0..51.2 MB region
    // that A1/h1/hbn occupy later (stream-ordered: tables dead before conv_x_bf).
    char* base = (char*)d_ws;
    // --- transient CSC tables (dead after fill_kernel) ---
    u16*   cnt_h  = (u16*)  (base + 0);             // NC*N u16 = 10.24 MB
    float* deg_p  = (float*)(base + 10240000);      // ND*N f32 = 10.24 MB
    int*   baseT  = (int*)  (base + 20480000);      // NC*N i32 = 20.48 MB (ends 40.96 MB)
    // --- persistent activations (written after CSC build) ---
    u16*   A1     = (u16*)  (base + 0);             // N*512 bf16 = 20.48 MB
    u16*   Hc     = A1;                             // aliased (A1 dead after GEMM1)
    float* h1     = (float*)(base + 20480000);      // N*256 fp32 = 20.48 MB
    float* h2     = h1;                             // aliased
    u16*   hbn    = (u16*)  (base + 40960000);      // N*256 bf16 = 10.24 MB
    u16*   bb2    = (u16*)  (base + 51200000);      // N*128 bf16 = 5.12 MB
    u16*   bb1    = (u16*)  (base + 56320000);
    u16*   pbuf   = (u16*)  (base + 61440000);
    u16*   W1t    = (u16*)  (base + 66560000);      // 256*512 bf16
    u16*   W2t    = (u16*)  (base + 66822144);      // 512*256 bf16
    int2*  epair  = (int2*) (base + 67084288);      // E*8 = 5.12 MB (ends 72204288)
    int*   rowptr = (int*)  (base + 72204288);      // N+1
    int*   tot    = (int*)  (base + 72284304);      // N
    float* dis    = (float*)(base + 72364304);      // N
    float* bns    = (float*)(base + 72444304);      // 256
    float* bnq     = bns + 256;
    float* bnscale = bnq + 256;
    float* bnshift = bnscale + 256;

    dim3 blk(256);

    // --- CSC build (zero global atomics, full-chip grids) ---
    cnt_hist<<<dim3(NC), blk, 0, stream>>>(ei, cnt_h, E, N);
    deg_hist<<<dim3(ND), blk, 0, stream>>>(ei, ew, deg_p, E, N);
    conv_w_both<<<dim3((512 * 256 + 4 * 256 * 128 + 255) / 256), blk, 0, stream>>>(W1, W1t, W2, W2t);
    reduce_dis<<<dim3((N + 255) / 256), blk, 0, stream>>>(cnt_h, deg_p, tot, dis, N);
    scan_kernel<<<dim3(1), blk, 0, stream>>>(tot, rowptr, N);
    mkbase<<<dim3((N + 255) / 256), blk, 0, stream>>>(rowptr, cnt_h, baseT, N);
    fill_kernel<<<dim3(NC), blk, 0, stream>>>(ei, ew, dis, baseT, epair, E, N);

    dim3 gS(((N << 4) + 255) / 256);   // spmm grid: 16 threads/node

    // --- layer 1: A1 = [x|T1|T2|T3] bf16, ld 512 (forward recursion) ---
    conv_x_bf<<<dim3((N * 128 + 255) / 256), blk, 0, stream>>>(x, A1, N * 128, 128, 512);
    spmm_cl<<<gS, blk, 0, stream>>>(rowptr, epair, A1 + 0,   512, nullptr,  512, 0.f,
                                    nullptr, 512, 0.f, A1 + 128, 512, nullptr, 0, N, 1.0f);
    spmm_cl<<<gS, blk, 0, stream>>>(rowptr, epair, A1 + 128, 512, A1 + 0,   512, -1.f,
                                    nullptr, 512, 0.f, A1 + 256, 512, nullptr, 0, N, 2.0f);
    spmm_cl<<<gS, blk, 0, stream>>>(rowptr, epair, A1 + 256, 512, A1 + 128, 512, -1.f,
                                    nullptr, 512, 0.f, A1 + 384, 512, nullptr, 0, N, 2.0f);

    // --- GEMM1: h1 = relu(A1 @ W1 + b1)  [M=20000, N=256, K=512] fp32 out ---
    gemm_mfma<<<dim3((N + GBM - 1) / GBM, CL1_F / GBN), blk, 0, stream>>>(
        A1, W1t, b1, h1, N, CL1_F, 512, 0);

    // --- BN1: stats(h1) -> apply -> hbn bf16 (N x 256) ---
    hipMemsetAsync(bns, 0, 2 * 256 * sizeof(float), stream);
    bn_stats<<<dim3((N + BN_ROWS - 1) / BN_ROWS), dim3(CL1_F), 0, stream>>>(h1, N, CL1_F, bns, bnq);
    bn_final<<<dim3(1), dim3(CL1_F), 0, stream>>>(bns, bnq, gamma1, beta1, bnscale, bnshift, CL1_F, 1.0f / N);
    bn_apply_bf<<<dim3((N * CL1_F + 255) / 256), blk, 0, stream>>>(h1, bnscale, bnshift, hbn, N * CL1_F, CL1_F);

    // --- GEMM2: Hc = hbn @ Wcat  [M=20000, N=512, K=256] bf16 out (S_k at Hc + k*128) ---
    gemm_mfma<<<dim3((N + GBM - 1) / GBM, 512 / GBN), blk, 0, stream>>>(
        hbn, W2t, nullptr, Hc, N, 512, 256, 1);

    // --- layer 2 via Clenshaw: all spmms on F=128 ---
    spmm_cl<<<gS, blk, 0, stream>>>(rowptr, epair, Hc + 384, 512, Hc + 256, 512, 1.f,
                                    nullptr, 512, 0.f, bb2, 128, nullptr, 0, N, 2.0f);
    spmm_cl<<<gS, blk, 0, stream>>>(rowptr, epair, bb2, 128, Hc + 384, 512, -1.f,
                                    Hc + 128, 512, 1.f, bb1, 128, nullptr, 0, N, 2.0f);
    spmm_cl<<<gS, blk, 0, stream>>>(rowptr, epair, bb1, 128, bb2, 128, -1.f,
                                    Hc + 0, 512, 1.f, pbuf, 128, b2, 1, N, 1.0f);

    // --- BN2: stats(pbuf bf16) -> apply -> h2 fp32 (N x 128) ---
    hipMemsetAsync(bns, 0, 2 * 256 * sizeof(float), stream);
    bn_stats_bf<<<dim3((N + BN_ROWS - 1) / BN_ROWS), dim3(CL2_F), 0, stream>>>(pbuf, N, CL2_F, bns, bnq);
    bn_final<<<dim3(1), dim3(CL2_F), 0, stream>>>(bns, bnq, gamma2, beta2, bnscale, bnshift, CL2_F, 1.0f / N);
    bn_apply_bf2f<<<dim3((N * CL2_F + 255) / 256), blk, 0, stream>>>(pbuf, bnscale, bnshift, h2, N * CL2_F, CL2_F);

    // --- final linear ---
    final_linear<<<dim3((N * OUT_F + 255) / 256), blk, 0, stream>>>(h2, Wlin, blin, out, N);
}

// Round 7
// 434.868 us; speedup vs baseline: 22.9680x; 1.0984x over previous
//
#include <hip/hip_runtime.h>
#include <cstdint>
#include <cstddef>

// Problem constants (match reference)
#define NNODES 20000
#define NEDGES 640000
#define IN_F   128
#define CL1_F  256
#define CL2_F  128
#define OUT_F  10
#define BN_EPS 1e-5f

#define NC     256                // edge chunks for cnt/fill (2500 edges each)
#define CE     (NEDGES / NC)
#define ND     128                // edge chunks for deg (5000 edges each)
#define DE     (NEDGES / ND)
#define HALFN  10000              // node half-range (deg_hist only)

typedef unsigned short u16;

// ---------------- bf16 helpers ----------------

__device__ __forceinline__ float bf2f(u16 u) {
    union { uint32_t i; float f; } v; v.i = ((uint32_t)u) << 16; return v.f;
}
__device__ __forceinline__ u16 f2bf(float f) {
    union { float f; uint32_t i; } v; v.f = f;
    uint32_t r = v.i + 0x7fffu + ((v.i >> 16) & 1u);   // RNE
    return (u16)(r >> 16);
}
__device__ __forceinline__ void bf2x2(uint32_t u, float& lo, float& hi) {
    union { uint32_t i; float f; } a, b;
    a.i = u << 16; b.i = u & 0xffff0000u;
    lo = a.f; hi = b.f;
}
__device__ __forceinline__ uint32_t f2bf2(float lo, float hi) {
    return (uint32_t)f2bf(lo) | ((uint32_t)f2bf(hi) << 16);
}
__device__ __forceinline__ void unpack8(uint4 v, float* o) {
    bf2x2(v.x, o[0], o[1]); bf2x2(v.y, o[2], o[3]);
    bf2x2(v.z, o[4], o[5]); bf2x2(v.w, o[6], o[7]);
}

// ---------------- CSC build: full-parallel LDS histograms ----------------

__launch_bounds__(256)
__global__ void cnt_hist(const int* __restrict__ ei, u16* __restrict__ cnt_h, int E, int N) {
    __shared__ uint32_t scnt[NNODES / 2];   // 40 KB
    int chunk = blockIdx.x;
    int e0 = chunk * CE, e1 = e0 + CE;
    for (int i = threadIdx.x; i < NNODES / 2; i += 256) scnt[i] = 0;
    __syncthreads();
    for (int e = e0 + threadIdx.x; e < e1; e += 256) {
        int c = ei[E + e];
        atomicAdd(&scnt[c >> 1], 1u << ((c & 1) * 16));
    }
    __syncthreads();
    for (int i = threadIdx.x; i < N; i += 256)
        cnt_h[(size_t)chunk * N + i] = (u16)((scnt[i >> 1] >> ((i & 1) * 16)) & 0xffffu);
}

__launch_bounds__(256)
__global__ void deg_hist(const int* __restrict__ ei, const float* __restrict__ ew,
                         float* __restrict__ deg_p, int E, int N) {
    __shared__ float sdeg[HALFN];           // 40 KB
    int b = blockIdx.x;
    int e0 = b * DE, e1 = e0 + DE;
    for (int half = 0; half < 2; ++half) {
        int lo = half * HALFN;
        for (int i = threadIdx.x; i < HALFN; i += 256) sdeg[i] = 0.f;
        __syncthreads();
        for (int e = e0 + threadIdx.x; e < e1; e += 256) {
            int r = ei[e];
            int ri = r - lo;
            if ((unsigned)ri < HALFN) {
                int c = ei[E + e];
                float w = (r == c) ? 0.0f : ew[e];
                atomicAdd(&sdeg[ri], w);
            }
        }
        __syncthreads();
        for (int i = threadIdx.x; i < HALFN; i += 256)
            deg_p[(size_t)b * N + lo + i] = sdeg[i];
        __syncthreads();
    }
}

__global__ void reduce_dis(const u16* __restrict__ cnt_h, const float* __restrict__ deg_p,
                           int* __restrict__ tot, float* __restrict__ dis, int N) {
    int i = blockIdx.x * blockDim.x + threadIdx.x;
    if (i >= N) return;
    int t = 0;
#pragma unroll 8
    for (int c = 0; c < NC; ++c) t += cnt_h[(size_t)c * N + i];
    float d = 0.f;
#pragma unroll 8
    for (int b = 0; b < ND; ++b) d += deg_p[(size_t)b * N + i];
    tot[i] = t;
    dis[i] = (d > 0.0f) ? (1.0f / sqrtf(d)) : 0.0f;
}

__global__ void scan_kernel(const int* __restrict__ tot, int* __restrict__ rowptr, int N) {
    __shared__ int sums[256];
    int t = threadIdx.x;
    int per = (N + 255) / 256;
    int s0 = t * per, s1 = min(s0 + per, N);
    int s = 0;
    for (int i = s0; i < s1; ++i) s += tot[i];
    sums[t] = s;
    __syncthreads();
    if (t == 0) {
        int run = 0;
        for (int i = 0; i < 256; ++i) { int v = sums[i]; sums[i] = run; run += v; }
        rowptr[N] = run;
    }
    __syncthreads();
    int run = sums[t];
    for (int i = s0; i < s1; ++i) { rowptr[i] = run; run += tot[i]; }
}

__global__ void mkbase(const int* __restrict__ rowptr, const u16* __restrict__ cnt_h,
                       int* __restrict__ baseT, int N) {
    int i = blockIdx.x * blockDim.x + threadIdx.x;
    if (i >= N) return;
    int run = rowptr[i];
#pragma unroll 8
    for (int c = 0; c < NC; ++c) {
        baseT[(size_t)c * N + i] = run;
        run += cnt_h[(size_t)c * N + i];
    }
}

// fill CSC: packed 4-byte records (src u16 | bf16 weight << 16)
__launch_bounds__(256)
__global__ void fill_kernel(const int* __restrict__ ei, const float* __restrict__ ew,
                            const float* __restrict__ dis, const int* __restrict__ baseT,
                            uint32_t* __restrict__ erec, int E, int N) {
    __shared__ uint32_t srank[NNODES / 2];  // 40 KB
    int chunk = blockIdx.x;
    int e0 = chunk * CE, e1 = e0 + CE;
    for (int i = threadIdx.x; i < NNODES / 2; i += 256) srank[i] = 0;
    __syncthreads();
    for (int e = e0 + threadIdx.x; e < e1; e += 256) {
        int r = ei[e];
        int c = ei[E + e];
        float w = (r == c) ? 0.0f : ew[e];
        float wn = -(dis[r] * w * dis[c]);   // * (2/lambda_max) = *1
        int sh = (c & 1) * 16;
        uint32_t old = atomicAdd(&srank[c >> 1], 1u << sh);
        int rank = (old >> sh) & 0xffff;
        int pos = baseT[(size_t)chunk * N + c] + rank;
        erec[pos] = (uint32_t)r | ((uint32_t)f2bf(wn) << 16);
    }
}

// ---------------- conversions ----------------

__global__ void conv_x_bf(const float* __restrict__ x, u16* __restrict__ dst,
                          int n_elems, int F, int ld) {
    int i = blockIdx.x * blockDim.x + threadIdx.x;
    if (i >= n_elems) return;
    int n = i / F, f = i - n * F;
    dst[(size_t)n * ld + f] = f2bf(x[i]);
}

// W1 (4,128,256) -> W1t[256][512];  W2 (4,256,128) -> W2t[512][256]
__global__ void conv_w_both(const float* __restrict__ W1, u16* __restrict__ W1t,
                            const float* __restrict__ W2, u16* __restrict__ W2t) {
    int i = blockIdx.x * blockDim.x + threadIdx.x;
    const int S1 = 512 * 256;
    const int S2 = 4 * 256 * 128;
    if (i < S1) {
        int k = i / 256, n = i - k * 256;
        W1t[(size_t)n * 512 + k] = f2bf(W1[i]);
    } else if (i < S1 + S2) {
        int j = i - S1;
        int kc = j / (256 * 128);
        int rem = j - kc * 256 * 128;
        int ci = rem / 128, co = rem - ci * 128;
        W2t[(size_t)(kc * 128 + co) * 256 + ci] = f2bf(W2[j]);
    }
}

// ---------------- general spmm (CSC gather, F=128, bf16 io, fp32 accum) ----------------
// tout[n] = s * sum_p w[p]*tin[src[p]] + c1*t1[n] + c2*t2[n]  (+bias, relu if flag)
__launch_bounds__(256)
__global__ void spmm_cl(const int* __restrict__ rowptr, const uint32_t* __restrict__ erec,
                        const u16* __restrict__ tin, int ldi,
                        const u16* __restrict__ t1, int ld1, float c1,
                        const u16* __restrict__ t2, int ld2, float c2,
                        u16* __restrict__ tout, int ldo,
                        const float* __restrict__ bias, int doReluBias,
                        int N, float s) {
    int gid = blockIdx.x * blockDim.x + threadIdx.x;
    int n = gid >> 4;
    if (n >= N) return;
    int f = (gid & 15) << 3;
    int p = rowptr[n], pe = rowptr[n + 1];
    float acc[8] = {};
    // unroll-4: 4 record loads (contiguous), then 4 independent row loads
    for (; p + 3 < pe; p += 4) {
        uint32_t r0 = erec[p], r1 = erec[p + 1], r2 = erec[p + 2], r3 = erec[p + 3];
        uint4 v0 = *(const uint4*)(tin + (size_t)(r0 & 0xffffu) * ldi + f);
        uint4 v1 = *(const uint4*)(tin + (size_t)(r1 & 0xffffu) * ldi + f);
        uint4 v2 = *(const uint4*)(tin + (size_t)(r2 & 0xffffu) * ldi + f);
        uint4 v3 = *(const uint4*)(tin + (size_t)(r3 & 0xffffu) * ldi + f);
        float w0 = bf2f((u16)(r0 >> 16)), w1 = bf2f((u16)(r1 >> 16));
        float w2 = bf2f((u16)(r2 >> 16)), w3 = bf2f((u16)(r3 >> 16));
        float fa[8];
        unpack8(v0, fa);
#pragma unroll
        for (int q = 0; q < 8; ++q) acc[q] += w0 * fa[q];
        unpack8(v1, fa);
#pragma unroll
        for (int q = 0; q < 8; ++q) acc[q] += w1 * fa[q];
        unpack8(v2, fa);
#pragma unroll
        for (int q = 0; q < 8; ++q) acc[q] += w2 * fa[q];
        unpack8(v3, fa);
#pragma unroll
        for (int q = 0; q < 8; ++q) acc[q] += w3 * fa[q];
    }
    for (; p < pe; ++p) {
        uint32_t r0 = erec[p];
        uint4 v0 = *(const uint4*)(tin + (size_t)(r0 & 0xffffu) * ldi + f);
        float w0 = bf2f((u16)(r0 >> 16));
        float fa[8];
        unpack8(v0, fa);
#pragma unroll
        for (int q = 0; q < 8; ++q) acc[q] += w0 * fa[q];
    }
#pragma unroll
    for (int q = 0; q < 8; ++q) acc[q] *= s;
    if (t1) {
        uint4 v = *(const uint4*)(t1 + (size_t)n * ld1 + f);
        float fv[8]; unpack8(v, fv);
#pragma unroll
        for (int q = 0; q < 8; ++q) acc[q] += c1 * fv[q];
    }
    if (t2) {
        uint4 v = *(const uint4*)(t2 + (size_t)n * ld2 + f);
        float fv[8]; unpack8(v, fv);
#pragma unroll
        for (int q = 0; q < 8; ++q) acc[q] += c2 * fv[q];
    }
    if (doReluBias) {
#pragma unroll
        for (int q = 0; q < 8; ++q) acc[q] = fmaxf(acc[q] + bias[f + q], 0.0f);
    }
    uint4 o;
    o.x = f2bf2(acc[0], acc[1]);
    o.y = f2bf2(acc[2], acc[3]);
    o.z = f2bf2(acc[4], acc[5]);
    o.w = f2bf2(acc[6], acc[7]);
    *(uint4*)(tout + (size_t)n * ldo + f) = o;
}

// ---------------- bf16 MFMA GEMM ----------------
// C = A[M,K] @ Bt[N,K]^T (+bias) (relu opt); out fp32 or bf16.

typedef __attribute__((ext_vector_type(8))) short short8;
typedef __attribute__((ext_vector_type(4))) float floatx4;

#define GBM 64
#define GBN 64
#define GBK 64

__launch_bounds__(256)
__global__ void gemm_mfma(const u16* __restrict__ A, const u16* __restrict__ Bt,
                          const float* __restrict__ bias, void* __restrict__ Cout,
                          int M, int N, int K, int doRelu, int outBf) {
    __shared__ __align__(16) u16 As[GBM][GBK + 8];
    __shared__ __align__(16) u16 Bs[GBN][GBK + 8];

    int tid = threadIdx.x;
    int lane = tid & 63;
    int wave = tid >> 6;
    int wm = (wave & 1) * 32;
    int wn = (wave >> 1) * 32;
    int rowBase = blockIdx.x * GBM;
    int colBase = blockIdx.y * GBN;

    floatx4 acc[2][2];
#pragma unroll
    for (int i = 0; i < 2; ++i)
#pragma unroll
        for (int j = 0; j < 2; ++j) {
            acc[i][j][0] = 0.f; acc[i][j][1] = 0.f; acc[i][j][2] = 0.f; acc[i][j][3] = 0.f;
        }

    int sr = tid >> 3;
    int sc = (tid & 7) * 8;

    for (int k0 = 0; k0 < K; k0 += GBK) {
#pragma unroll
        for (int h = 0; h < 2; ++h) {
            int r = sr + h * 32;
            int gm = rowBase + r;
            uint4 v = make_uint4(0, 0, 0, 0);
            if (gm < M) v = *(const uint4*)(A + (size_t)gm * K + k0 + sc);
            *(uint4*)&As[r][sc] = v;
            int gn = colBase + r;
            uint4 w = *(const uint4*)(Bt + (size_t)gn * K + k0 + sc);
            *(uint4*)&Bs[r][sc] = w;
        }
        __syncthreads();

        int mrow = lane & 15;
        int kq = (lane >> 4) * 8;
#pragma unroll
        for (int kk = 0; kk < GBK; kk += 32) {
            short8 af[2], bfr[2];
#pragma unroll
            for (int i = 0; i < 2; ++i) af[i] = *(const short8*)&As[wm + i * 16 + mrow][kk + kq];
#pragma unroll
            for (int j = 0; j < 2; ++j) bfr[j] = *(const short8*)&Bs[wn + j * 16 + mrow][kk + kq];
#pragma unroll
            for (int i = 0; i < 2; ++i)
#pragma unroll
                for (int j = 0; j < 2; ++j)
                    acc[i][j] = __builtin_amdgcn_mfma_f32_16x16x32_bf16(af[i], bfr[j], acc[i][j], 0, 0, 0);
        }
        __syncthreads();
    }

    int cn0 = colBase + wn + (lane & 15);
    int rq = (lane >> 4) * 4;
    float* Cf = (float*)Cout;
    u16*   Cb = (u16*)Cout;
#pragma unroll
    for (int i = 0; i < 2; ++i) {
#pragma unroll
        for (int r = 0; r < 4; ++r) {
            int m = rowBase + wm + i * 16 + rq + r;
            if (m >= M) continue;
#pragma unroll
            for (int j = 0; j < 2; ++j) {
                int n = cn0 + j * 16;
                float v = acc[i][j][r];
                if (bias) v += bias[n];
                if (doRelu) v = fmaxf(v, 0.0f);
                if (outBf) Cb[(size_t)m * N + n] = f2bf(v);
                else       Cf[(size_t)m * N + n] = v;
            }
        }
    }
}

// ---------------- batchnorm (stats only; applies are folded into GEMMs) ----------------

#define BN_ROWS 64
__global__ void bn_stats_bf(const u16* __restrict__ h, int N, int C,
                            float* __restrict__ sums, float* __restrict__ sumsq) {
    int c = threadIdx.x;
    int r0 = blockIdx.x * BN_ROWS;
    int r1 = min(r0 + BN_ROWS, N);
    float s = 0.f, q = 0.f;
    for (int r = r0; r < r1; ++r) {
        float v = bf2f(h[(size_t)r * C + c]);
        s += v;
        q += v * v;
    }
    atomicAdd(&sums[c], s);
    atomicAdd(&sumsq[c], q);
}

__global__ void bn_final(const float* __restrict__ sums, const float* __restrict__ sumsq,
                         const float* __restrict__ gamma, const float* __restrict__ beta,
                         float* __restrict__ scale, float* __restrict__ shift, int C, float invN) {
    int c = threadIdx.x + blockIdx.x * blockDim.x;
    if (c >= C) return;
    float m = sums[c] * invN;
    float var = sumsq[c] * invN - m * m;
    float sc = gamma[c] / sqrtf(var + BN_EPS);
    scale[c] = sc;
    shift[c] = beta[c] - m * sc;
}

// fold BN1 into W2t (in place): W2t[n][k] *= scale[k]; rowvec[n] = sum_k shift[k]*W2t_orig[n][k]
__launch_bounds__(64)
__global__ void fold_w2(u16* __restrict__ W2t, const float* __restrict__ scale,
                        const float* __restrict__ shift, float* __restrict__ rowvec) {
    int n = blockIdx.x;            // 0..511
    int lane = threadIdx.x;        // 0..63
    float part = 0.f;
#pragma unroll
    for (int j = 0; j < 4; ++j) {
        int k = lane + j * 64;
        float wf = bf2f(W2t[(size_t)n * 256 + k]);
        part += shift[k] * wf;
        W2t[(size_t)n * 256 + k] = f2bf(wf * scale[k]);
    }
#pragma unroll
    for (int off = 32; off > 0; off >>= 1) part += __shfl_down(part, off);
    if (lane == 0) rowvec[n] = part;
}

// fold BN2 into Wlin: Wlp[o][c] = Wlin[o][c]*scale[c]; blin_p[o] = blin[o] + sum_c shift[c]*Wlin[o][c]
__launch_bounds__(128)
__global__ void fold_lin(const float* __restrict__ Wlin, const float* __restrict__ blin,
                         const float* __restrict__ scale, const float* __restrict__ shift,
                         float* __restrict__ Wlp, float* __restrict__ blin_p) {
    __shared__ float red[2];
    int o = blockIdx.x;            // 0..9
    int c = threadIdx.x;           // 0..127
    float wf = Wlin[(size_t)o * 128 + c];
    Wlp[(size_t)o * 128 + c] = wf * scale[c];
    float part = shift[c] * wf;
#pragma unroll
    for (int off = 32; off > 0; off >>= 1) part += __shfl_down(part, off);
    if ((c & 63) == 0) red[c >> 6] = part;
    __syncthreads();
    if (c == 0) blin_p[o] = blin[o] + red[0] + red[1];
}

// ---------------- final linear (bf16 input, BN folded) ----------------

__global__ void final_linear_bf(const u16* __restrict__ g, const float* __restrict__ Wlp,
                                const float* __restrict__ blin_p, float* __restrict__ out, int N) {
    __shared__ float Ws[OUT_F * CL2_F];
    __shared__ float bs[OUT_F];
    for (int i = threadIdx.x; i < OUT_F * CL2_F; i += 256) Ws[i] = Wlp[i];
    if (threadIdx.x < OUT_F) bs[threadIdx.x] = blin_p[threadIdx.x];
    __syncthreads();
    int idx = blockIdx.x * 256 + threadIdx.x;
    if (idx >= N * OUT_F) return;
    int n = idx / OUT_F, o = idx - n * OUT_F;
    const u16* gr = g + (size_t)n * CL2_F;
    const float* wr = Ws + o * CL2_F;
    float acc = 0.f;
#pragma unroll 8
    for (int f = 0; f < CL2_F; ++f) acc += bf2f(gr[f]) * wr[f];
    out[idx] = acc + bs[o];
}

// ---------------- host launch ----------------

extern "C" void kernel_launch(void* const* d_in, const int* in_sizes, int n_in,
                              void* d_out, int out_size, void* d_ws, size_t ws_size,
                              hipStream_t stream) {
    const float* x      = (const float*)d_in[0];
    const int*   ei     = (const int*)d_in[1];
    const float* ew     = (const float*)d_in[2];
    const float* W1     = (const float*)d_in[3];
    const float* b1     = (const float*)d_in[4];
    const float* W2     = (const float*)d_in[5];
    const float* b2     = (const float*)d_in[6];
    const float* gamma1 = (const float*)d_in[7];
    const float* beta1  = (const float*)d_in[8];
    const float* gamma2 = (const float*)d_in[9];
    const float* beta2  = (const float*)d_in[10];
    const float* Wlin   = (const float*)d_in[11];
    const float* blin   = (const float*)d_in[12];
    float* out = (float*)d_out;

    const int N = NNODES, E = NEDGES;

    // workspace (~49.5 MB). CSC-build tables (cnt_h/deg_p/baseT, 0..40.96 MB)
    // alias activation buffers written strictly after fill_kernel.
    char* base = (char*)d_ws;
    // --- transient CSC tables ---
    u16*     cnt_h  = (u16*)    (base + 0);           // NC*N u16 = 10.24 MB
    float*   deg_p  = (float*)  (base + 10240000);    // ND*N f32 = 10.24 MB
    int*     baseT  = (int*)    (base + 20480000);    // NC*N i32 = 20.48 MB (ends 40.96 MB)
    // --- persistent (written after CSC build) ---
    u16*     A1     = (u16*)    (base + 0);           // N*512 bf16 = 20.48 MB
    u16*     Hc     = A1;                             // aliased (A1 dead after GEMM1)
    u16*     h1bf   = (u16*)    (base + 20480000);    // N*256 bf16 = 10.24 MB
    u16*     pbuf   = (u16*)    (base + 30720000);    // N*128 bf16 = 5.12 MB
    u16*     bb2    = (u16*)    (base + 35840000);    // N*128 bf16
    u16*     bb1    = (u16*)    (base + 40960000);    // N*128 bf16 (past transients' end)
    uint32_t* erec  = (uint32_t*)(base + 46080000);   // E*4 = 2.56 MB
    u16*     W1t    = (u16*)    (base + 48640000);    // 256*512 bf16 = 262144
    u16*     W2t    = (u16*)    (base + 48902144);    // 512*256 bf16 = 262144
    float*   Wlp    = (float*)  (base + 49164288);    // 10*128 f32 = 5120
    float*   rowvec = (float*)  (base + 49169408);    // 512 f32 = 2048
    float*   blin_p = (float*)  (base + 49171456);    // 10 f32 (pad to 64)
    int*     rowptr = (int*)    (base + 49171520);    // N+1
    int*     tot    = (int*)    (base + 49251536);    // N
    float*   dis    = (float*)  (base + 49331536);    // N
    float*   bns    = (float*)  (base + 49411536);    // 256
    float*   bnq     = bns + 256;
    float*   bnscale = bnq + 256;
    float*   bnshift = bnscale + 256;

    dim3 blk(256);

    // --- CSC build (zero global atomics, full-chip grids) ---
    cnt_hist<<<dim3(NC), blk, 0, stream>>>(ei, cnt_h, E, N);
    deg_hist<<<dim3(ND), blk, 0, stream>>>(ei, ew, deg_p, E, N);
    conv_w_both<<<dim3((512 * 256 + 4 * 256 * 128 + 255) / 256), blk, 0, stream>>>(W1, W1t, W2, W2t);
    reduce_dis<<<dim3((N + 255) / 256), blk, 0, stream>>>(cnt_h, deg_p, tot, dis, N);
    scan_kernel<<<dim3(1), blk, 0, stream>>>(tot, rowptr, N);
    mkbase<<<dim3((N + 255) / 256), blk, 0, stream>>>(rowptr, cnt_h, baseT, N);
    fill_kernel<<<dim3(NC), blk, 0, stream>>>(ei, ew, dis, baseT, erec, E, N);

    dim3 gS(((N << 4) + 255) / 256);   // spmm grid: 16 threads/node

    // --- layer 1: A1 = [x|T1|T2|T3] bf16, ld 512 ---
    conv_x_bf<<<dim3((N * 128 + 255) / 256), blk, 0, stream>>>(x, A1, N * 128, 128, 512);
    spmm_cl<<<gS, blk, 0, stream>>>(rowptr, erec, A1 + 0,   512, nullptr,  512, 0.f,
                                    nullptr, 512, 0.f, A1 + 128, 512, nullptr, 0, N, 1.0f);
    spmm_cl<<<gS, blk, 0, stream>>>(rowptr, erec, A1 + 128, 512, A1 + 0,   512, -1.f,
                                    nullptr, 512, 0.f, A1 + 256, 512, nullptr, 0, N, 2.0f);
    spmm_cl<<<gS, blk, 0, stream>>>(rowptr, erec, A1 + 256, 512, A1 + 128, 512, -1.f,
                                    nullptr, 512, 0.f, A1 + 384, 512, nullptr, 0, N, 2.0f);

    // --- GEMM1: h1bf = relu(A1 @ W1 + b1) bf16  [M=20000, N=256, K=512] ---
    gemm_mfma<<<dim3((N + GBM - 1) / GBM, CL1_F / GBN), blk, 0, stream>>>(
        A1, W1t, b1, h1bf, N, CL1_F, 512, 1, 1);

    // --- BN1 stats -> fold into W2t + rowvec ---
    hipMemsetAsync(bns, 0, 2 * 256 * sizeof(float), stream);
    bn_stats_bf<<<dim3((N + BN_ROWS - 1) / BN_ROWS), dim3(CL1_F), 0, stream>>>(h1bf, N, CL1_F, bns, bnq);
    bn_final<<<dim3(1), dim3(CL1_F), 0, stream>>>(bns, bnq, gamma1, beta1, bnscale, bnshift, CL1_F, 1.0f / N);
    fold_w2<<<dim3(512), dim3(64), 0, stream>>>(W2t, bnscale, bnshift, rowvec);

    // --- GEMM2: Hc = h1bf @ W2t' + rowvec  [M=20000, N=512, K=256] bf16 out ---
    gemm_mfma<<<dim3((N + GBM - 1) / GBM, 512 / GBN), blk, 0, stream>>>(
        h1bf, W2t, rowvec, Hc, N, 512, 256, 0, 1);

    // --- layer 2 via Clenshaw (F=128 spmms) ---
    spmm_cl<<<gS, blk, 0, stream>>>(rowptr, erec, Hc + 384, 512, Hc + 256, 512, 1.f,
                                    nullptr, 512, 0.f, bb2, 128, nullptr, 0, N, 2.0f);
    spmm_cl<<<gS, blk, 0, stream>>>(rowptr, erec, bb2, 128, Hc + 384, 512, -1.f,
                                    Hc + 128, 512, 1.f, bb1, 128, nullptr, 0, N, 2.0f);
    spmm_cl<<<gS, blk, 0, stream>>>(rowptr, erec, bb1, 128, bb2, 128, -1.f,
                                    Hc + 0, 512, 1.f, pbuf, 128, b2, 1, N, 1.0f);

    // --- BN2 stats -> fold into Wlin ---
    hipMemsetAsync(bns, 0, 2 * 256 * sizeof(float), stream);
    bn_stats_bf<<<dim3((N + BN_ROWS - 1) / BN_ROWS), dim3(CL2_F), 0, stream>>>(pbuf, N, CL2_F, bns, bnq);
    bn_final<<<dim3(1), dim3(CL2_F), 0, stream>>>(bns, bnq, gamma2, beta2, bnscale, bnshift, CL2_F, 1.0f / N);
    fold_lin<<<dim3(OUT_F), dim3(CL2_F), 0, stream>>>(Wlin, blin, bnscale, bnshift, Wlp, blin_p);

    // --- final linear (bf16 input, folded BN) ---
    final_linear_bf<<<dim3((N * OUT_F + 255) / 256), blk, 0, stream>>>(pbuf, Wlp, blin_p, out, N);
}